// Round 6
// baseline (628.618 us; speedup 1.0000x reference)
//
#include <hip/hip_runtime.h>
#include <hip/hip_bf16.h>
#include <math.h>

typedef unsigned short ushort_t;
typedef __attribute__((ext_vector_type(8))) short bf16x8;
typedef __attribute__((ext_vector_type(4))) float f32x4;

#define LOG2E 1.4426950408889634f

// ---------------- helpers ----------------
__device__ __forceinline__ float sigf(float x) {
  x = fminf(fmaxf(x, -30.f), 30.f);
  return 1.f / (1.f + __expf(-x));
}
__device__ __forceinline__ ushort_t f2bf(float x) {
  unsigned int b = __float_as_uint(x);
  unsigned int lsb = (b >> 16) & 1u;
  b += 0x7fffu + lsb;
  return (ushort_t)(b >> 16);
}
__device__ __forceinline__ float bf2f(ushort_t u) {
  return __uint_as_float(((unsigned int)u) << 16);
}
// gate scale for exp2-form activations: rows of gate g (pos&3==2) carry
// 2*log2e, others log2e. Applied at every pre-activation producer.
__device__ __forceinline__ float gsc(int g3) {
  return (g3 == 2) ? (2.f * LOG2E) : LOG2E;
}

#define NPIX 3600
// gate-row permutation: LSTM row-space position rho holds real gate row
// G(rho) = (rho&3)*128 + (rho>>2)  => per cell c, gates i,f,g,o sit at
// positions 4c..4c+3.
__device__ __forceinline__ int gperm(int rho) {
  return ((rho & 3) << 7) + (rho >> 2);
}

// ------- gvec[b][n] = wih0[:,128:] @ gf[b] / 3600 (permuted, gate-scaled) ---
__global__ __launch_bounds__(256) void gvec_kernel(
    const float* __restrict__ wih0, const float* __restrict__ gf,
    float* __restrict__ gvec) {
  int i = blockIdx.x * 256 + threadIdx.x;  // 16384
  int b = i >> 9, n = i & 511;
  const float* wr = wih0 + gperm(n) * 192 + 128;
  const float* g = gf + b * 64;
  float a = 0.f;
#pragma unroll
  for (int k = 0; k < 64; ++k) a = fmaf(wr[k], g[k], a);
  gvec[i] = a * (1.f / 3600.f) * gsc(n & 3);
}

// ---- front: wprep (blocks 0-1988) + conv1 (1989-16388) + stats (16389-) ----
__global__ __launch_bounds__(256) void front_kernel(
    const float* __restrict__ mv, const float* __restrict__ c1w,
    const float* __restrict__ c1b, const float* __restrict__ bg1,
    const float* __restrict__ bb1, ushort_t* __restrict__ x1out,
    const float* __restrict__ boxes, const int* __restrict__ ids,
    const float* __restrict__ agg_w1, const float* __restrict__ agg_b1,
    const float* __restrict__ agg_w2, const float* __restrict__ agg_b2,
    const float* __restrict__ bx_w1, const float* __restrict__ bx_b1,
    const float* __restrict__ bx_w2, const float* __restrict__ bx_b2,
    const float* __restrict__ id_table, ushort_t* __restrict__ obj_out,
    const float* __restrict__ conv2_w, const float* __restrict__ conv3_w,
    const float* __restrict__ wih0, const float* __restrict__ projW,
    const float* __restrict__ projb, const float* __restrict__ l0_b,
    const float* __restrict__ hbw1, const float* __restrict__ hcw1,
    const float* __restrict__ htw1, const float* __restrict__ htw2,
    const float* __restrict__ hbb1, const float* __restrict__ hcb1,
    const float* __restrict__ htb1, ushort_t* __restrict__ wc2,
    ushort_t* __restrict__ wc3, ushort_t* __restrict__ wAp,
    float* __restrict__ l0bp, ushort_t* __restrict__ whid,
    ushort_t* __restrict__ wt2, float* __restrict__ bhid) {
  if (blockIdx.x < 1989) {
    // ---- weight prep ----
    int i = blockIdx.x * 256 + threadIdx.x;
    if (i < 18432) {  // conv2 w -> [oc][kt][ic] bf16
      int oc = i / 288, r = i % 288, kt = r / 32, ic = r % 32;
      wc2[i] = f2bf(conv2_w[((oc * 32 + ic) * 3 + kt / 3) * 3 + kt % 3]);
      return;
    }
    i -= 18432;
    if (i < 36864) {  // conv3 w -> [oc][c][kt][ic] bf16
      int oc = i / 576, r = i % 576, c = r / 288, r2 = r % 288;
      int kt = r2 / 32, icl = r2 % 32, ic = c * 32 + icl;
      wc3[i] = f2bf(conv3_w[((oc * 64 + ic) * 3 + kt / 3) * 3 + kt % 3]);
      return;
    }
    i -= 36864;
    if (i < 98304) {  // W' = wih0[:, :128] @ projW, permuted + gate-scaled
      int n = i / 192, k = i % 192;
      int src = gperm(n);
      float a = 0.f;
      if (k < 160) {
        const float* wr = wih0 + src * 192;
        for (int j = 0; j < 128; ++j) a = fmaf(wr[j], projW[j * 160 + k], a);
      }
      wAp[i] = f2bf(a * gsc(n & 3));
      return;
    }
    i -= 98304;
    if (i < 512) {  // l0b' = l0_b + wih0[:, :128] @ proj_b, permuted + scaled
      int src = gperm(i);
      float a = l0_b[src];
      const float* wr = wih0 + src * 192;
      for (int j = 0; j < 128; ++j) a = fmaf(wr[j], projb[j], a);
      l0bp[i] = a * gsc(i & 3);
      return;
    }
    i -= 512;
    if (i < 98304) {  // concat head hidden weights
      int row = i >> 7, c = i & 127;
      float v = (row < 256)   ? hbw1[row * 128 + c]
                : (row < 512) ? hcw1[(row - 256) * 128 + c]
                              : htw1[(row - 512) * 128 + c];
      whid[i] = f2bf(v);
      return;
    }
    i -= 98304;
    if (i < 256000) {
      wt2[i] = f2bf(htw2[i]);
      return;
    }
    i -= 256000;
    if (i < 768)
      bhid[i] = (i < 256) ? hbb1[i] : (i < 512) ? hcb1[i - 256] : htb1[i - 512];
    return;
  }
  int bx = blockIdx.x - 1989;
  if (bx < 14400) {
    // ---- conv1: 2->32, naive, fused BN+ReLU, bf16 out ----
    int idx = bx * 256 + threadIdx.x;
    int x = idx % 60;
    int y = (idx / 60) % 60;
    int oc = (idx / 3600) % 32;
    int b = idx / (3600 * 32);
    float acc = 0.f;
#pragma unroll
    for (int ic = 0; ic < 2; ++ic) {
      const float* src = mv + (b * 2 + ic) * NPIX;
      const float* wp = c1w + (oc * 2 + ic) * 9;
#pragma unroll
      for (int ky = 0; ky < 3; ++ky) {
        int gy = y + ky - 1;
        if (gy < 0 || gy >= 60) continue;
#pragma unroll
        for (int kx = 0; kx < 3; ++kx) {
          int gx = x + kx - 1;
          if (gx < 0 || gx >= 60) continue;
          acc = fmaf(src[gy * 60 + gx], wp[ky * 3 + kx], acc);
        }
      }
    }
    float s = bg1[oc] * rsqrtf(1.f + 1e-5f);
    float v = fmaf(acc, s, fmaf(c1b[oc], s, bb1[oc]));
    x1out[idx] = f2bf(fmaxf(v, 0.f));
    return;
  }
  // ---- box stats + small MLPs: 2 boxes per block ----
  __shared__ float obj[2][160];
  __shared__ float hm[2][32];
  __shared__ float hbx[2][32];
  __shared__ float stats[2][8];
  __shared__ float boxf[2][4];
  __shared__ float red[2][2][8];
  int h = threadIdx.x >> 7;
  int t = threadIdx.x & 127;
  int blk = (bx - 14400) * 2 + h;  // box index 0..9599
  int b = blk / 300;
  float bx0 = boxes[blk * 4 + 0], by0 = boxes[blk * 4 + 1];
  float bx1 = boxes[blk * 4 + 2], by1 = boxes[blk * 4 + 3];
  const float HI = (float)(60.0 - 1e-6);
  float gx1 = fminf(fmaxf(bx0 * 60.f, 0.f), HI);
  float gy1 = fminf(fmaxf(by0 * 60.f, 0.f), HI);
  float gx2 = fminf(fmaxf(bx1 * 60.f, 0.f), HI);
  float gy2 = fminf(fmaxf(by1 * 60.f, 0.f), HI);
  float fx1 = floorf(gx1), fy1 = floorf(gy1);
  float fx2 = fmaxf(fx1 + 1.f, ceilf(gx2));
  float fy2 = fmaxf(fy1 + 1.f, ceilf(gy2));
  int ix1 = (int)fx1, iy1 = (int)fy1, ix2 = (int)fx2, iy2 = (int)fy2;
  int w = ix2 - ix1, hgt = iy2 - iy1;
  int area = w * hgt;
  float s0 = 0.f, s1 = 0.f, q0 = 0.f, q1 = 0.f;
  float mn0 = 1e9f, mn1 = 1e9f, mx0 = -1e9f, mx1 = -1e9f;
  const float* mv0 = mv + b * 2 * NPIX;
  const float* mv1 = mv0 + NPIX;
  for (int i = t; i < area; i += 128) {
    int r = i / w, cc = i - r * w;
    int yy = iy1 + r, xx = ix1 + cc;
    float v0 = mv0[yy * 60 + xx];
    float v1 = mv1[yy * 60 + xx];
    s0 += v0; q0 += v0 * v0; mn0 = fminf(mn0, v0); mx0 = fmaxf(mx0, v0);
    s1 += v1; q1 += v1 * v1; mn1 = fminf(mn1, v1); mx1 = fmaxf(mx1, v1);
  }
#pragma unroll
  for (int off = 32; off; off >>= 1) {
    s0 += __shfl_down(s0, off); s1 += __shfl_down(s1, off);
    q0 += __shfl_down(q0, off); q1 += __shfl_down(q1, off);
    mn0 = fminf(mn0, __shfl_down(mn0, off));
    mn1 = fminf(mn1, __shfl_down(mn1, off));
    mx0 = fmaxf(mx0, __shfl_down(mx0, off));
    mx1 = fmaxf(mx1, __shfl_down(mx1, off));
  }
  if ((t & 63) == 0) {
    int wv = t >> 6;
    red[h][wv][0] = s0; red[h][wv][1] = s1;
    red[h][wv][2] = q0; red[h][wv][3] = q1;
    red[h][wv][4] = mn0; red[h][wv][5] = mn1;
    red[h][wv][6] = mx0; red[h][wv][7] = mx1;
  }
  __syncthreads();
  if (t == 0) {
    float S0 = red[h][0][0] + red[h][1][0], S1 = red[h][0][1] + red[h][1][1];
    float Q0 = red[h][0][2] + red[h][1][2], Q1 = red[h][0][3] + red[h][1][3];
    float MN0 = fminf(red[h][0][4], red[h][1][4]);
    float MN1 = fminf(red[h][0][5], red[h][1][5]);
    float MX0 = fmaxf(red[h][0][6], red[h][1][6]);
    float MX1 = fmaxf(red[h][0][7], red[h][1][7]);
    float cnt = (float)area;
    float mean0 = S0 / cnt, mean1 = S1 / cnt;
    float var0 = (Q0 - cnt * mean0 * mean0) / fmaxf(cnt - 1.f, 1.f);
    float var1 = (Q1 - cnt * mean1 * mean1) / fmaxf(cnt - 1.f, 1.f);
    float sd0 = (cnt > 1.f) ? sqrtf(fmaxf(var0, 1e-12f)) : 0.f;
    float sd1 = (cnt > 1.f) ? sqrtf(fmaxf(var1, 1e-12f)) : 0.f;
    stats[h][0] = mean0; stats[h][1] = mean1; stats[h][2] = sd0;
    stats[h][3] = sd1; stats[h][4] = MN0; stats[h][5] = MX0;
    stats[h][6] = MN1; stats[h][7] = MX1;
    boxf[h][0] = bx0; boxf[h][1] = by0; boxf[h][2] = bx1; boxf[h][3] = by1;
  }
  __syncthreads();
  if (t < 32) {
    float a = agg_b1[t];
#pragma unroll
    for (int k = 0; k < 8; ++k) a = fmaf(stats[h][k], agg_w1[t * 8 + k], a);
    hm[h][t] = fmaxf(a, 0.f);
  } else if (t < 64) {
    int j = t - 32;
    float a = bx_b1[j];
#pragma unroll
    for (int k = 0; k < 4; ++k) a = fmaf(boxf[h][k], bx_w1[j * 4 + k], a);
    hbx[h][j] = fmaxf(a, 0.f);
  }
  __syncthreads();
  if (t < 64) {
    float a = bx_b2[t];
#pragma unroll
    for (int k = 0; k < 32; ++k) a = fmaf(hbx[h][k], bx_w2[t * 32 + k], a);
    obj[h][t] = a;
  } else {
    int j = t - 64;
    float a = agg_b2[j];
#pragma unroll
    for (int k = 0; k < 32; ++k) a = fmaf(hm[h][k], agg_w2[j * 32 + k], a);
    obj[h][96 + j] = a;
  }
  if (t < 32) {
    int id = ids[blk];
    id = min(max(id, 0), 999);
    obj[h][64 + t] = id_table[id * 32 + t];
  }
  __syncthreads();
  obj_out[(size_t)blk * 192 + t] = f2bf(obj[h][t]);
  if (t < 32) {
    obj_out[(size_t)blk * 192 + 128 + t] = f2bf(obj[h][128 + t]);
    obj_out[(size_t)blk * 192 + 160 + t] = 0;
  }
}

// ---------------- conv2/conv3: MFMA implicit-GEMM, pre-laid-out bf16 w ------
template <int CIN, bool POOL>
__global__ __launch_bounds__(256) void conv_mfma_kernel(
    const ushort_t* __restrict__ in, const ushort_t* __restrict__ wc,
    const float* __restrict__ cb, const float* __restrict__ bg,
    const float* __restrict__ bb, ushort_t* __restrict__ out,
    float* __restrict__ gf) {
  constexpr int NCHUNK = CIN / 32;
  __shared__ ushort_t in_lds[18 * 18 * 40];
  int tid = threadIdx.x;
  int wv = tid >> 6, lane = tid & 63;
  int col = lane & 15, kg = lane >> 4;
  int b = blockIdx.y, tile = blockIdx.x;
  int tq = tile >> 2, tr = tile & 3;
  int ty0 = tq * 16 - (tq == 3 ? 4 : 0);
  int tx0 = tr * 16 - (tr == 3 ? 4 : 0);
  int oc = wv * 16 + col;

  bf16x8 bw[NCHUNK * 9];
#pragma unroll
  for (int c = 0; c < NCHUNK; ++c)
#pragma unroll
    for (int kt = 0; kt < 9; ++kt)
      bw[c * 9 + kt] = *(const bf16x8*)(wc + oc * (NCHUNK * 288) + c * 288 +
                                        kt * 32 + kg * 8);

  f32x4 acc[16];
#pragma unroll
  for (int m = 0; m < 16; ++m) acc[m] = (f32x4){0.f, 0.f, 0.f, 0.f};

  for (int c = 0; c < NCHUNK; ++c) {
    if (c) __syncthreads();
    for (int i = tid; i < 18 * 18 * 32; i += 256) {
      int ic = i / 324, rem = i % 324;
      int yy = rem / 18, xx = rem % 18;
      int gy = ty0 + yy - 1, gx = tx0 + xx - 1;
      ushort_t v = 0;
      if (gy >= 0 && gy < 60 && gx >= 0 && gx < 60)
        v = in[((size_t)(b * CIN + c * 32 + ic) * 60 + gy) * 60 + gx];
      in_lds[(yy * 18 + xx) * 40 + ic] = v;
    }
    __syncthreads();
#pragma unroll
    for (int kt = 0; kt < 9; ++kt) {
      int ky = kt / 3, kx = kt % 3;
#pragma unroll
      for (int m = 0; m < 16; ++m) {
        bf16x8 af =
            *(const bf16x8*)(&in_lds[((m + ky) * 18 + col + kx) * 40 + kg * 8]);
        acc[m] = __builtin_amdgcn_mfma_f32_16x16x32_bf16(af, bw[c * 9 + kt],
                                                         acc[m], 0, 0, 0);
      }
    }
  }
  float s = bg[oc] * rsqrtf(1.f + 1e-5f);
  float bias = fmaf(cb[oc], s, bb[oc]);
  float pool = 0.f;
#pragma unroll
  for (int m = 0; m < 16; ++m) {
    float vv[4];
#pragma unroll
    for (int r = 0; r < 4; ++r) vv[r] = fmaxf(fmaf(acc[m][r], s, bias), 0.f);
    if (POOL) {
      bool ymask = (tq != 3) || (m >= 4);
#pragma unroll
      for (int r = 0; r < 4; ++r) {
        int px = kg * 4 + r;
        bool xmask = (tr != 3) || (px >= 4);
        if (ymask && xmask) pool += vv[r];
      }
    } else {
      ushort_t st[4];
#pragma unroll
      for (int r = 0; r < 4; ++r) st[r] = f2bf(vv[r]);
      int yy = ty0 + m, xx = tx0 + kg * 4;
      *(uint2*)(&out[((size_t)(b * 64 + oc) * 60 + yy) * 60 + xx]) =
          *(uint2*)st;
    }
  }
  if (POOL) {
    pool += __shfl_xor(pool, 16);
    pool += __shfl_xor(pool, 32);
    if (lane < 16) atomicAdd(&gf[b * 64 + oc], pool);
  }
}

// ---------------- bf16-W MFMA GEMM: C = act(A@W^T + b [+ gvec]) -------------
template <int ACT, bool OBF16, bool GVEC>
__global__ __launch_bounds__(256) void gemm_bf16w_kernel(
    const ushort_t* __restrict__ A, int lda, const ushort_t* __restrict__ W,
    const float* __restrict__ bias, void* __restrict__ C, int ldc, int M,
    int N, int K, const float* __restrict__ gvec) {
  __shared__ ushort_t As[128 * 64];
  __shared__ ushort_t Ws[64 * 64];
  int tid = threadIdx.x;
  int wv = tid >> 6, lane = tid & 63;
  int col = lane & 15, kg = lane >> 4;
  int wm = wv >> 1, wn = wv & 1;
  int m0 = blockIdx.x * 128, n0 = blockIdx.y * 64;
  f32x4 acc[4][2];
#pragma unroll
  for (int i = 0; i < 4; ++i)
#pragma unroll
    for (int j = 0; j < 2; ++j) acc[i][j] = (f32x4){0.f, 0.f, 0.f, 0.f};

  int nk = K >> 6;
  for (int kc = 0; kc < nk; ++kc) {
    if (kc) __syncthreads();
#pragma unroll
    for (int q = 0; q < 4; ++q) {
      int idx = q * 256 + tid;
      int row = idx >> 3, ch = idx & 7;
      uint4 v =
          *(const uint4*)(A + (size_t)(m0 + row) * lda + kc * 64 + ch * 8);
      *(uint4*)(&As[row * 64 + ((ch * 8) ^ ((row & 7) << 3))]) = v;
    }
#pragma unroll
    for (int q = 0; q < 2; ++q) {
      int idx = q * 256 + tid;
      int row = idx >> 3, ch = idx & 7;
      int n = n0 + row;
      uint4 v = make_uint4(0, 0, 0, 0);
      if (n < N) v = *(const uint4*)(W + (size_t)n * K + kc * 64 + ch * 8);
      *(uint4*)(&Ws[row * 64 + ((ch * 8) ^ ((row & 7) << 3))]) = v;
    }
    __syncthreads();
#pragma unroll
    for (int ks = 0; ks < 2; ++ks) {
      bf16x8 bfr[2], afr[4];
#pragma unroll
      for (int ni = 0; ni < 2; ++ni) {
        int row = wn * 32 + ni * 16 + col;
        bfr[ni] = *(const bf16x8*)(
            &Ws[row * 64 + ((ks * 32 + kg * 8) ^ ((row & 7) << 3))]);
      }
#pragma unroll
      for (int mi = 0; mi < 4; ++mi) {
        int row = wm * 64 + mi * 16 + col;
        afr[mi] = *(const bf16x8*)(
            &As[row * 64 + ((ks * 32 + kg * 8) ^ ((row & 7) << 3))]);
      }
#pragma unroll
      for (int mi = 0; mi < 4; ++mi)
#pragma unroll
        for (int ni = 0; ni < 2; ++ni)
          acc[mi][ni] = __builtin_amdgcn_mfma_f32_16x16x32_bf16(
              afr[mi], bfr[ni], acc[mi][ni], 0, 0, 0);
    }
  }
#pragma unroll
  for (int ni = 0; ni < 2; ++ni) {
    int n = n0 + wn * 32 + ni * 16 + col;
    float bn = (n < N) ? bias[n] : 0.f;
#pragma unroll
    for (int mi = 0; mi < 4; ++mi) {
      int mbase = m0 + wm * 64 + mi * 16 + kg * 4;
#pragma unroll
      for (int r = 0; r < 4; ++r) {
        float v = acc[mi][ni][r] + bn;
        if (GVEC) v += gvec[((mbase + r) / 300) * 512 + n];
        if (ACT == 1) v = fmaxf(v, 0.f);
        if (n < N) {
          if (OBF16)
            ((ushort_t*)C)[(size_t)(mbase + r) * ldc + n] = f2bf(v);
          else
            ((float*)C)[(size_t)(mbase + r) * ldc + n] = v;
        }
      }
    }
  }
}

// ------------- fused 2-layer LSTM scan + flag-gated tail consumers ----------
// Producers (blocks 0..23) = v9 core unchanged: L0 (0-7), L1 (8-15, now
// publishes y1 progress every 30 steps: vmcnt(0)+syncthreads+flag[g*32+17]),
// u-blocks (16-23). NEW consumers (24..103): block 24+8*ck+g handles group g
// chunk ck (30 steps, 120 rows) -> same XCD residue as its producer L1 block
// 8+g, keeping y1 reads L2-local. Consumer work: GEMM1 hid=relu(y1@whid^T+b)
// (written into pre0's DEAD row slots, stride 1024 ushort: L0 consumed those
// rows >=30 steps before the flag fires), small B/C heads, GEMM2
// outT=hid2@wt2^T+b. All hidden in the LSTM's 300us shadow except the last
// chunk (~10-25us tail) -- replaces ~80-110us of serial tail dispatches.
#define LSTM_BAR() asm volatile("s_waitcnt lgkmcnt(0)\n\ts_barrier" ::: "memory")

__global__ __launch_bounds__(512) void lstm_fused_kernel(
    const float* pre0,               // [32][300][512] f32, permuted+scaled
    const float* __restrict__ whh0,  // [512,128]
    const float* __restrict__ wih1,  // [512,128]
    const float* __restrict__ whh1,  // [512,128]
    const float* __restrict__ b1,    // [512]
    float* __restrict__ pre1,        // [32][300][512] f32, permuted+scaled
    ushort_t* __restrict__ y0,       // [32][300][128] bf16 (L0 -> u)
    ushort_t* __restrict__ y1,       // [32][300][128] bf16 (L1 -> consumers)
    float* __restrict__ outH, float* __restrict__ outC,
    unsigned int* __restrict__ flags,  // [8*32]
    ushort_t* hid16,                   // == (ushort_t*)pre0, slots of 1024
    const ushort_t* __restrict__ whid, const ushort_t* __restrict__ wt2,
    const float* __restrict__ bhid, const float* __restrict__ hbw2,
    const float* __restrict__ hbb2, const float* __restrict__ hcw2,
    const float* __restrict__ hcb2, const float* __restrict__ htb2,
    float* __restrict__ outB, float* __restrict__ outCls,
    float* __restrict__ outT) {
  __shared__ ushort_t smem[30720];  // 61440 B union (h_lds | As/Ws | As2)
  int tid = threadIdx.x;
  int w = tid >> 6, lane = tid & 63;
  int col = lane & 15, kg = lane >> 4;
  int bat = col & 3, q = col >> 2;
  int cell = (4 * w + q) * 4 + kg;
  float wsc = gsc(col & 3);
  ushort_t (*h_lds)[4][160] = (ushort_t(*)[4][160])smem;

  if (blockIdx.x < 8) {
    // ---------------- layer 0 ----------------
    int g = blockIdx.x;
    int b0 = g * 4;
    unsigned int* flagp = &flags[g * 32];
    for (int i = tid; i < 2 * 4 * 160; i += 512) smem[i] = 0;
    bf16x8 aW0[4][4];
#pragma unroll
    for (int j = 0; j < 4; ++j) {
      int rho = (4 * w + j) * 16 + col;
      int src = gperm(rho);
#pragma unroll
      for (int kt = 0; kt < 4; ++kt) {
        const float* s1 = whh0 + src * 128 + kt * 32 + kg * 8;
        bf16x8 f1;
#pragma unroll
        for (int qq = 0; qq < 8; ++qq) f1[qq] = (short)f2bf(s1[qq] * wsc);
        aW0[j][kt] = f1;
      }
    }
    const float* pg = pre0 + (size_t)(b0 + bat) * 300 * 512 + 4 * cell;
    ushort_t* yg0 = y0 + ((size_t)(b0 + bat) * 300) * 128 + cell;
    float c = 0.f, hout = 0.f;
    f32x4 p0v = *(const f32x4*)(pg);
    f32x4 p1v = *(const f32x4*)(pg + 512);
    __syncthreads();

    for (int s = 0; s < 300; ++s) {
      const ushort_t* hb = h_lds[s & 1][bat];
      bf16x8 bfr[4];
#pragma unroll
      for (int kt = 0; kt < 4; ++kt)
        bfr[kt] = *(const bf16x8*)(hb + kt * 32 + kg * 8);
      f32x4 a0 = {0.f, 0.f, 0.f, 0.f}, a1 = a0, a2 = a0, a3 = a0;
#pragma unroll
      for (int kt = 0; kt < 4; ++kt) {
        a0 = __builtin_amdgcn_mfma_f32_16x16x32_bf16(aW0[0][kt], bfr[kt], a0, 0, 0, 0);
        a1 = __builtin_amdgcn_mfma_f32_16x16x32_bf16(aW0[1][kt], bfr[kt], a1, 0, 0, 0);
        a2 = __builtin_amdgcn_mfma_f32_16x16x32_bf16(aW0[2][kt], bfr[kt], a2, 0, 0, 0);
        a3 = __builtin_amdgcn_mfma_f32_16x16x32_bf16(aW0[3][kt], bfr[kt], a3, 0, 0, 0);
      }
      f32x4 z = a0;
      if (q == 1) z = a1;
      if (q == 2) z = a2;
      if (q == 3) z = a3;
      {
        float zi = z[0] + p0v[0];
        float zf = z[1] + p0v[1];
        float zg = z[2] + p0v[2];
        float zo = z[3] + p0v[3];
        float vi = __builtin_amdgcn_rcpf(1.f + __builtin_amdgcn_exp2f(-zi));
        float vf = __builtin_amdgcn_rcpf(1.f + __builtin_amdgcn_exp2f(-zf));
        float vg = 1.f - 2.f * __builtin_amdgcn_rcpf(
                              __builtin_amdgcn_exp2f(zg) + 1.f);
        float vo = __builtin_amdgcn_rcpf(1.f + __builtin_amdgcn_exp2f(-zo));
        c = vf * c + vi * vg;
        hout = vo * (1.f - 2.f * __builtin_amdgcn_rcpf(
                             __builtin_amdgcn_exp2f(2.f * LOG2E * c) + 1.f));
        ushort_t hv = f2bf(hout);
        h_lds[(s + 1) & 1][bat][cell] = hv;
        __builtin_nontemporal_store(hv, yg0 + (size_t)s * 128);
        p0v = p1v;
        int sn = (s + 2 < 300) ? s + 2 : 299;
        p1v = *(const f32x4*)(pg + (size_t)sn * 512);
      }
      asm volatile("s_waitcnt vmcnt(6)" ::: "memory");
      LSTM_BAR();
      if (tid == 0 && s >= 3)
        __hip_atomic_store(flagp, (unsigned int)(s - 3), __ATOMIC_RELAXED,
                           __HIP_MEMORY_SCOPE_AGENT);
    }
    asm volatile("s_waitcnt vmcnt(0)" ::: "memory");
    __syncthreads();
    if (tid == 0)
      __hip_atomic_store(flagp, 300u, __ATOMIC_RELAXED,
                         __HIP_MEMORY_SCOPE_AGENT);
    outH[(b0 + bat) * 128 + cell] = hout;
    outC[(b0 + bat) * 128 + cell] = c;
  } else if (blockIdx.x < 16) {
    // ---------------- layer 1 ----------------
    int g = blockIdx.x - 8;
    int b0 = g * 4;
    unsigned int* flagp = &flags[g * 32 + 16];
    unsigned int* flagy1 = &flags[g * 32 + 17];
    for (int i = tid; i < 2 * 4 * 160; i += 512) smem[i] = 0;
    bf16x8 aW[4][4];
#pragma unroll
    for (int j = 0; j < 4; ++j) {
      int rho = (4 * w + j) * 16 + col;
      int src = gperm(rho);
#pragma unroll
      for (int kt = 0; kt < 4; ++kt) {
        const float* s1 = whh1 + src * 128 + kt * 32 + kg * 8;
        bf16x8 f1;
#pragma unroll
        for (int qq = 0; qq < 8; ++qq) f1[qq] = (short)f2bf(s1[qq] * wsc);
        aW[j][kt] = f1;
      }
    }
    float bi = b1[cell] * LOG2E, bff = b1[128 + cell] * LOG2E;
    float bgg = b1[256 + cell] * (2.f * LOG2E), boo = b1[384 + cell] * LOG2E;
    const float* pg = pre1 + (size_t)(b0 + bat) * 300 * 512 + 4 * cell;
    ushort_t* yg = y1 + (size_t)(b0 + bat) * 300 * 128 + cell;
    float c = 0.f, hout = 0.f;
    unsigned int fc = 0;
    f32x4 p0v, p1v;
    do {
      fc = __hip_atomic_load(flagp, __ATOMIC_RELAXED,
                             __HIP_MEMORY_SCOPE_AGENT);
      if (fc < 1) __builtin_amdgcn_s_sleep(2);
    } while (fc < 1);
    asm volatile("" ::: "memory");
    p0v = __builtin_nontemporal_load((const f32x4*)(pg));
    while (fc < 2) {
      fc = __hip_atomic_load(flagp, __ATOMIC_RELAXED,
                             __HIP_MEMORY_SCOPE_AGENT);
      if (fc < 2) __builtin_amdgcn_s_sleep(2);
    }
    asm volatile("" ::: "memory");
    p1v = __builtin_nontemporal_load((const f32x4*)(pg + 512));
    __syncthreads();

    for (int t = 0; t < 300; ++t) {
      unsigned int fcn = __hip_atomic_load(flagp, __ATOMIC_RELAXED,
                                           __HIP_MEMORY_SCOPE_AGENT);
      const ushort_t* hb = h_lds[t & 1][bat];
      bf16x8 bfr[4];
#pragma unroll
      for (int kt = 0; kt < 4; ++kt)
        bfr[kt] = *(const bf16x8*)(hb + kt * 32 + kg * 8);
      f32x4 a0 = {0.f, 0.f, 0.f, 0.f}, a1 = a0, a2 = a0, a3 = a0;
#pragma unroll
      for (int kt = 0; kt < 4; ++kt) {
        a0 = __builtin_amdgcn_mfma_f32_16x16x32_bf16(aW[0][kt], bfr[kt], a0, 0, 0, 0);
        a1 = __builtin_amdgcn_mfma_f32_16x16x32_bf16(aW[1][kt], bfr[kt], a1, 0, 0, 0);
        a2 = __builtin_amdgcn_mfma_f32_16x16x32_bf16(aW[2][kt], bfr[kt], a2, 0, 0, 0);
        a3 = __builtin_amdgcn_mfma_f32_16x16x32_bf16(aW[3][kt], bfr[kt], a3, 0, 0, 0);
      }
      f32x4 z = a0;
      if (q == 1) z = a1;
      if (q == 2) z = a2;
      if (q == 3) z = a3;
      {
        float zi = z[0] + p0v[0] + bi;
        float zf = z[1] + p0v[1] + bff;
        float zg = z[2] + p0v[2] + bgg;
        float zo = z[3] + p0v[3] + boo;
        float vi = __builtin_amdgcn_rcpf(1.f + __builtin_amdgcn_exp2f(-zi));
        float vf = __builtin_amdgcn_rcpf(1.f + __builtin_amdgcn_exp2f(-zf));
        float vg = 1.f - 2.f * __builtin_amdgcn_rcpf(
                              __builtin_amdgcn_exp2f(zg) + 1.f);
        float vo = __builtin_amdgcn_rcpf(1.f + __builtin_amdgcn_exp2f(-zo));
        c = vf * c + vi * vg;
        hout = vo * (1.f - 2.f * __builtin_amdgcn_rcpf(
                             __builtin_amdgcn_exp2f(2.f * LOG2E * c) + 1.f));
        ushort_t hv = f2bf(hout);
        h_lds[(t + 1) & 1][bat][cell] = hv;
        yg[(size_t)t * 128] = hv;
        p0v = p1v;
        if (t + 2 < 300) {
          unsigned int need = (unsigned int)(t + 3);
          if (fcn > fc) fc = fcn;
          if (fc < need) {
            do {
              fc = __hip_atomic_load(flagp, __ATOMIC_RELAXED,
                                     __HIP_MEMORY_SCOPE_AGENT);
              if (fc < need) __builtin_amdgcn_s_sleep(2);
            } while (fc < need);
            asm volatile("" ::: "memory");
          }
          p1v = __builtin_nontemporal_load(
              (const f32x4*)(pg + (size_t)(t + 2) * 512));
        }
      }
      if ((t % 30) == 29) {  // publish y1 progress for tail consumers
        asm volatile("s_waitcnt vmcnt(0)" ::: "memory");
        __syncthreads();
        if (tid == 0)
          __hip_atomic_store(flagy1, (unsigned int)(t + 1), __ATOMIC_RELAXED,
                             __HIP_MEMORY_SCOPE_AGENT);
      }
      LSTM_BAR();
    }
    outH[4096 + (b0 + bat) * 128 + cell] = hout;
    outC[4096 + (b0 + bat) * 128 + cell] = c;
  } else if (blockIdx.x < 24) {
    // ---------------- u-blocks: pre1[t] = Wih1 @ y0[t], 12-step chunks ------
    int g = blockIdx.x - 16;
    int b0 = g * 4;
    unsigned int* flag0 = &flags[g * 32];
    unsigned int* flag1 = &flags[g * 32 + 16];
    bf16x8 aU[4][4];
#pragma unroll
    for (int j = 0; j < 4; ++j) {
      int rho = (4 * w + j) * 16 + col;
      int src = gperm(rho);
#pragma unroll
      for (int kt = 0; kt < 4; ++kt) {
        const float* s2 = wih1 + src * 128 + kt * 32 + kg * 8;
        bf16x8 f2;
#pragma unroll
        for (int qq = 0; qq < 8; ++qq) f2[qq] = (short)f2bf(s2[qq] * wsc);
        aU[j][kt] = f2;
      }
    }
    int bb = col & 3;
    int ts = col >> 2;
    const ushort_t* yb = y0 + ((size_t)(b0 + bb) * 300) * 128 + kg * 8;
    unsigned int fc = 0;
    for (int t0 = 0; t0 < 300; t0 += 12) {
      unsigned int need = (unsigned int)(t0 + 11);
      while (fc < need) {
        fc = __hip_atomic_load(flag0, __ATOMIC_RELAXED,
                               __HIP_MEMORY_SCOPE_AGENT);
        if (fc < need) __builtin_amdgcn_s_sleep(2);
      }
      asm volatile("" ::: "memory");
      f32x4 acc[4][3];
#pragma unroll
      for (int j = 0; j < 4; ++j)
#pragma unroll
        for (int ct = 0; ct < 3; ++ct) acc[j][ct] = (f32x4){0.f, 0.f, 0.f, 0.f};
#pragma unroll
      for (int ct = 0; ct < 3; ++ct) {
        int t = t0 + ct * 4 + ts;
        bf16x8 bfr[4];
#pragma unroll
        for (int kt = 0; kt < 4; ++kt)
          bfr[kt] = __builtin_nontemporal_load(
              (const bf16x8*)(yb + (size_t)t * 128 + kt * 32));
#pragma unroll
        for (int kt = 0; kt < 4; ++kt) {
          acc[0][ct] = __builtin_amdgcn_mfma_f32_16x16x32_bf16(aU[0][kt], bfr[kt], acc[0][ct], 0, 0, 0);
          acc[1][ct] = __builtin_amdgcn_mfma_f32_16x16x32_bf16(aU[1][kt], bfr[kt], acc[1][ct], 0, 0, 0);
          acc[2][ct] = __builtin_amdgcn_mfma_f32_16x16x32_bf16(aU[2][kt], bfr[kt], acc[2][ct], 0, 0, 0);
          acc[3][ct] = __builtin_amdgcn_mfma_f32_16x16x32_bf16(aU[3][kt], bfr[kt], acc[3][ct], 0, 0, 0);
        }
      }
#pragma unroll
      for (int ct = 0; ct < 3; ++ct) {
        int t = t0 + ct * 4 + ts;
        float* pd = pre1 + ((size_t)(b0 + bb) * 300 + t) * 512 + kg * 4;
#pragma unroll
        for (int j = 0; j < 4; ++j)
          __builtin_nontemporal_store(acc[j][ct],
                                      (f32x4*)(pd + (4 * w + j) * 16));
      }
      asm volatile("s_waitcnt vmcnt(0)" ::: "memory");
      __syncthreads();
      if (tid == 0)
        __hip_atomic_store(flag1, (unsigned int)(t0 + 12), __ATOMIC_RELAXED,
                           __HIP_MEMORY_SCOPE_AGENT);
    }
  } else {
    // ------------- tail consumers: hid GEMM + heads + tid GEMM --------------
    int idx2 = blockIdx.x - 24;
    int g = idx2 & 7, ck = idx2 >> 3;  // same XCD residue as L1 block 8+g
    int b0 = g * 4, t0 = ck * 30;
    unsigned int* flagy = &flags[g * 32 + 17];
    unsigned int need = (unsigned int)(t0 + 30);
    unsigned int fc = 0;
    while (fc < need) {
      fc = __hip_atomic_load(flagy, __ATOMIC_RELAXED,
                             __HIP_MEMORY_SCOPE_AGENT);
      if (fc < need) __builtin_amdgcn_s_sleep(8);
    }
    asm volatile("" ::: "memory");
    int wm = w >> 2, wn = w & 3;
    int Rt[4][4];
    bool Vt[4][4];
#pragma unroll
    for (int mi = 0; mi < 4; ++mi)
#pragma unroll
      for (int r = 0; r < 4; ++r) {
        int m = wm * 64 + mi * 16 + kg * 4 + r;
        Vt[mi][r] = (m < 120);
        int mm = (m < 120) ? m : 119;
        Rt[mi][r] = (b0 + mm / 30) * 300 + t0 + mm % 30;
      }
    // ---- GEMM1: hid = relu(y1chunk @ whid^T + bhid) -> pre0 dead slots ----
    ushort_t* As = smem;          // [128][128]
    ushort_t* Wt = smem + 16384;  // [64][128]
    for (int i = tid; i < 2048; i += 512) {
      int r = i >> 4, ch = i & 15;
      uint4 v = make_uint4(0, 0, 0, 0);
      if (r < 120) {
        int R = (b0 + r / 30) * 300 + t0 + r % 30;
        v = *(const uint4*)(y1 + (size_t)R * 128 + ch * 8);
      }
      *(uint4*)(&As[r * 128 + ((ch * 8) ^ ((r & 7) << 3))]) = v;
    }
    __syncthreads();
    for (int nt = 0; nt < 12; ++nt) {
      if (nt) __syncthreads();
      for (int i = tid; i < 1024; i += 512) {
        int r = i >> 4, ch = i & 15;
        uint4 v = *(const uint4*)(whid + (size_t)(nt * 64 + r) * 128 + ch * 8);
        *(uint4*)(&Wt[r * 128 + ((ch * 8) ^ ((r & 7) << 3))]) = v;
      }
      __syncthreads();
      f32x4 acc[4];
#pragma unroll
      for (int mi = 0; mi < 4; ++mi) acc[mi] = (f32x4){0.f, 0.f, 0.f, 0.f};
      int rl = wn * 16 + col;
#pragma unroll
      for (int ks = 0; ks < 4; ++ks) {
        bf16x8 bfr = *(const bf16x8*)(
            &Wt[rl * 128 + ((ks * 32 + kg * 8) ^ ((rl & 7) << 3))]);
#pragma unroll
        for (int mi = 0; mi < 4; ++mi) {
          int rm = wm * 64 + mi * 16 + col;
          bf16x8 afr = *(const bf16x8*)(
              &As[rm * 128 + ((ks * 32 + kg * 8) ^ ((rm & 7) << 3))]);
          acc[mi] = __builtin_amdgcn_mfma_f32_16x16x32_bf16(afr, bfr, acc[mi],
                                                            0, 0, 0);
        }
      }
      int n = nt * 64 + wn * 16 + col;
      float bn = bhid[n];
#pragma unroll
      for (int mi = 0; mi < 4; ++mi)
#pragma unroll
        for (int r = 0; r < 4; ++r)
          if (Vt[mi][r]) {
            float v = fmaxf(acc[mi][r] + bn, 0.f);
            hid16[(size_t)Rt[mi][r] * 1024 + n] = f2bf(v);
          }
    }
    asm volatile("s_waitcnt vmcnt(0)" ::: "memory");
    __syncthreads();
    // ---- small heads (B: sigmoid x4, C: x2) ----
    for (int o = tid; o < 720; o += 512) {
      int m = o / 6, j = o % 6;
      int R = (b0 + m / 30) * 300 + t0 + m % 30;
      const ushort_t* hsrc = hid16 + (size_t)R * 1024 + (j < 4 ? 0 : 256);
      const float* wrow = (j < 4) ? hbw2 + j * 256 : hcw2 + (j - 4) * 256;
      float a = (j < 4) ? hbb2[j] : hcb2[j - 4];
      for (int k = 0; k < 256; k += 8) {
        uint4 hv = *(const uint4*)(hsrc + k);
        unsigned int wq[4] = {hv.x, hv.y, hv.z, hv.w};
#pragma unroll
        for (int qq = 0; qq < 4; ++qq) {
          a = fmaf(bf2f((ushort_t)(wq[qq] & 0xffff)), wrow[k + 2 * qq], a);
          a = fmaf(bf2f((ushort_t)(wq[qq] >> 16)), wrow[k + 2 * qq + 1], a);
        }
      }
      if (j < 4) outB[R * 4 + j] = sigf(a);
      else outCls[R * 2 + (j - 4)] = a;
    }
    __syncthreads();
    // ---- GEMM2: outT = hid2 @ wt2^T + ht_b2 ----
    ushort_t* As2 = smem;  // [120][256]
    for (int i = tid; i < 3840; i += 512) {
      int r = i >> 5, ch = i & 31;
      int R = (b0 + r / 30) * 300 + t0 + r % 30;
      uint4 v = *(const uint4*)(hid16 + (size_t)R * 1024 + 512 + ch * 8);
      *(uint4*)(&As2[r * 256 + ((ch * 8) ^ ((r & 7) << 3))]) = v;
    }
    __syncthreads();
    for (int nt = 0; nt < 16; ++nt) {
      f32x4 acc[4];
#pragma unroll
      for (int mi = 0; mi < 4; ++mi) acc[mi] = (f32x4){0.f, 0.f, 0.f, 0.f};
      int n = nt * 64 + wn * 16 + col;
      int nc = (n < 1000) ? n : 999;
#pragma unroll
      for (int ks = 0; ks < 8; ++ks) {
        bf16x8 bfr =
            *(const bf16x8*)(wt2 + (size_t)nc * 256 + ks * 32 + kg * 8);
#pragma unroll
        for (int mi = 0; mi < 4; ++mi) {
          int rm = wm * 64 + mi * 16 + col;
          int rc = (rm < 120) ? rm : 119;
          bf16x8 afr = *(const bf16x8*)(
              &As2[rc * 256 + ((ks * 32 + kg * 8) ^ ((rc & 7) << 3))]);
          acc[mi] = __builtin_amdgcn_mfma_f32_16x16x32_bf16(afr, bfr, acc[mi],
                                                            0, 0, 0);
        }
      }
      float bn = htb2[nc];
      bool nok = (n < 1000);
#pragma unroll
      for (int mi = 0; mi < 4; ++mi)
#pragma unroll
        for (int r = 0; r < 4; ++r)
          if (Vt[mi][r] && nok)
            outT[(size_t)Rt[mi][r] * 1000 + n] = acc[mi][r] + bn;
    }
  }
}

// ---------------- launch ----------------
extern "C" void kernel_launch(void* const* d_in, const int* in_sizes, int n_in,
                              void* d_out, int out_size, void* d_ws,
                              size_t ws_size, hipStream_t stream) {
  const float* mv = (const float*)d_in[0];
  const float* boxes = (const float*)d_in[1];
  const int* track_ids = (const int*)d_in[2];
  const float* conv1_w = (const float*)d_in[3];
  const float* conv1_b = (const float*)d_in[4];
  const float* bn1_g = (const float*)d_in[5];
  const float* bn1_b = (const float*)d_in[6];
  const float* conv2_w = (const float*)d_in[7];
  const float* conv2_b = (const float*)d_in[8];
  const float* bn2_g = (const float*)d_in[9];
  const float* bn2_b = (const float*)d_in[10];
  const float* conv3_w = (const float*)d_in[11];
  const float* conv3_b = (const float*)d_in[12];
  const float* bn3_g = (const float*)d_in[13];
  const float* bn3_b = (const float*)d_in[14];
  const float* agg_w1 = (const float*)d_in[15];
  const float* agg_b1 = (const float*)d_in[16];
  const float* agg_w2 = (const float*)d_in[17];
  const float* agg_b2 = (const float*)d_in[18];
  const float* bx_w1 = (const float*)d_in[19];
  const float* bx_b1 = (const float*)d_in[20];
  const float* bx_w2 = (const float*)d_in[21];
  const float* bx_b2 = (const float*)d_in[22];
  const float* id_table = (const float*)d_in[23];
  const float* proj_w = (const float*)d_in[24];
  const float* proj_b = (const float*)d_in[25];
  const float* l0_wih = (const float*)d_in[27];
  const float* l0_whh = (const float*)d_in[28];
  const float* l0_b = (const float*)d_in[29];
  const float* l1_wih = (const float*)d_in[30];
  const float* l1_whh = (const float*)d_in[31];
  const float* l1_b = (const float*)d_in[32];
  const float* hb_w1 = (const float*)d_in[33];
  const float* hb_b1 = (const float*)d_in[34];
  const float* hb_w2 = (const float*)d_in[35];
  const float* hb_b2 = (const float*)d_in[36];
  const float* hc_w1 = (const float*)d_in[37];
  const float* hc_b1 = (const float*)d_in[38];
  const float* hc_w2 = (const float*)d_in[39];
  const float* hc_b2 = (const float*)d_in[40];
  const float* ht_w1 = (const float*)d_in[41];
  const float* ht_b1 = (const float*)d_in[42];
  const float* ht_w2 = (const float*)d_in[43];
  const float* ht_b2 = (const float*)d_in[44];

  char* wsb = (char*)d_ws;
  ushort_t* x1u = (ushort_t*)(wsb + 0);          // 7,372,800 B
  ushort_t* x2u = (ushort_t*)(wsb + 7372800);    // 14,745,600 B
  float* pre0 = (float*)(wsb + 0);               // 19,660,800 B (alias convs;
                                                 // dead rows reused as hid)
  ushort_t* y0g = (ushort_t*)(wsb + 19660800);   // 2,457,600 B (x2u tail)
  float* gf = (float*)(wsb + 22118400);          // 8,192 B
  ushort_t* obj = (ushort_t*)(wsb + 22126592);   // 3,686,400 B
  float* pre1 = (float*)(wsb + 25812992);        // 19,660,800 B
  ushort_t* y1b = (ushort_t*)(wsb + 45473792);   // 2,457,600 B
  unsigned int* flags = (unsigned int*)(wsb + 47931392);  // 1,024 B
  ushort_t* wAp = (ushort_t*)(wsb + 47932416);   // 196,608 B
  ushort_t* whid = (ushort_t*)(wsb + 48129024);  // 196,608 B
  ushort_t* wt2 = (ushort_t*)(wsb + 48325632);   // 512,000 B
  float* bhid = (float*)(wsb + 48837632);        // 3,072 B
  float* l0bp = (float*)(wsb + 48840704);        // 2,048 B
  float* gvec = (float*)(wsb + 48842752);        // 65,536 B
  ushort_t* wc2 = (ushort_t*)(wsb + 48908288);   // 36,864 B
  ushort_t* wc3 = (ushort_t*)(wsb + 48945152);   // 73,728 B

  float* outB = (float*)d_out;    // [32,300,4]
  float* outC = outB + 38400;     // [32,300,2]
  float* outT = outB + 57600;     // [32,300,1000]
  float* outH = outB + 9657600;   // [2,32,128]
  float* outCc = outB + 9665792;  // [2,32,128]

  hipMemsetAsync(gf, 0, 2048 * sizeof(float), stream);
  hipMemsetAsync(flags, 0, 1024, stream);

  front_kernel<<<21189, 256, 0, stream>>>(
      mv, conv1_w, conv1_b, bn1_g, bn1_b, x1u, boxes, track_ids, agg_w1,
      agg_b1, agg_w2, agg_b2, bx_w1, bx_b1, bx_w2, bx_b2, id_table, obj,
      conv2_w, conv3_w, l0_wih, proj_w, proj_b, l0_b, hb_w1, hc_w1, ht_w1,
      ht_w2, hb_b1, hc_b1, ht_b1, wc2, wc3, wAp, l0bp, whid, wt2, bhid);
  conv_mfma_kernel<32, false><<<dim3(16, 32), 256, 0, stream>>>(
      x1u, wc2, conv2_b, bn2_g, bn2_b, x2u, nullptr);
  conv_mfma_kernel<64, true><<<dim3(16, 32), 256, 0, stream>>>(
      x2u, wc3, conv3_b, bn3_g, bn3_b, nullptr, gf);
  gvec_kernel<<<64, 256, 0, stream>>>(l0_wih, gf, gvec);
  gemm_bf16w_kernel<0, false, true><<<dim3(75, 8), 256, 0, stream>>>(
      obj, 192, wAp, l0bp, pre0, 512, 9600, 512, 192, gvec);
  lstm_fused_kernel<<<104, 512, 0, stream>>>(
      pre0, l0_whh, l1_wih, l1_whh, l1_b, pre1, y0g, y1b, outH, outCc, flags,
      (ushort_t*)pre0, whid, wt2, bhid, hb_w2, hb_b2, hc_w2, hc_b2, ht_b2,
      outB, outC, outT);
}

// Round 7
// 624.893 us; speedup vs baseline: 1.0060x; 1.0060x over previous
//
#include <hip/hip_runtime.h>
#include <hip/hip_bf16.h>
#include <math.h>

typedef unsigned short ushort_t;
typedef __attribute__((ext_vector_type(8))) short bf16x8;
typedef __attribute__((ext_vector_type(4))) float f32x4;

#define LOG2E 1.4426950408889634f

// ---------------- helpers ----------------
__device__ __forceinline__ float sigf(float x) {
  x = fminf(fmaxf(x, -30.f), 30.f);
  return 1.f / (1.f + __expf(-x));
}
__device__ __forceinline__ ushort_t f2bf(float x) {
  unsigned int b = __float_as_uint(x);
  unsigned int lsb = (b >> 16) & 1u;
  b += 0x7fffu + lsb;
  return (ushort_t)(b >> 16);
}
__device__ __forceinline__ float bf2f(ushort_t u) {
  return __uint_as_float(((unsigned int)u) << 16);
}
// gate scale for exp2-form activations: rows of gate g (pos&3==2) carry
// 2*log2e, others log2e. Applied at every pre-activation producer.
__device__ __forceinline__ float gsc(int g3) {
  return (g3 == 2) ? (2.f * LOG2E) : LOG2E;
}

#define NPIX 3600
// gate-row permutation: LSTM row-space position rho holds real gate row
// G(rho) = (rho&3)*128 + (rho>>2)  => per cell c, gates i,f,g,o sit at
// positions 4c..4c+3.
__device__ __forceinline__ int gperm(int rho) {
  return ((rho & 3) << 7) + (rho >> 2);
}

// ------- gvec[b][n] = wih0[:,128:] @ gf[b] / 3600 (permuted, gate-scaled) ---
__global__ __launch_bounds__(256) void gvec_kernel(
    const float* __restrict__ wih0, const float* __restrict__ gf,
    float* __restrict__ gvec) {
  int i = blockIdx.x * 256 + threadIdx.x;  // 16384
  int b = i >> 9, n = i & 511;
  const float* wr = wih0 + gperm(n) * 192 + 128;
  const float* g = gf + b * 64;
  float a = 0.f;
#pragma unroll
  for (int k = 0; k < 64; ++k) a = fmaf(wr[k], g[k], a);
  gvec[i] = a * (1.f / 3600.f) * gsc(n & 3);
}

// ---- front: wprep (blocks 0-1988) + conv1 (1989-16388) + stats (16389-) ----
__global__ __launch_bounds__(256) void front_kernel(
    const float* __restrict__ mv, const float* __restrict__ c1w,
    const float* __restrict__ c1b, const float* __restrict__ bg1,
    const float* __restrict__ bb1, ushort_t* __restrict__ x1out,
    const float* __restrict__ boxes, const int* __restrict__ ids,
    const float* __restrict__ agg_w1, const float* __restrict__ agg_b1,
    const float* __restrict__ agg_w2, const float* __restrict__ agg_b2,
    const float* __restrict__ bx_w1, const float* __restrict__ bx_b1,
    const float* __restrict__ bx_w2, const float* __restrict__ bx_b2,
    const float* __restrict__ id_table, ushort_t* __restrict__ obj_out,
    const float* __restrict__ conv2_w, const float* __restrict__ conv3_w,
    const float* __restrict__ wih0, const float* __restrict__ projW,
    const float* __restrict__ projb, const float* __restrict__ l0_b,
    const float* __restrict__ hbw1, const float* __restrict__ hcw1,
    const float* __restrict__ htw1, const float* __restrict__ htw2,
    const float* __restrict__ hbb1, const float* __restrict__ hcb1,
    const float* __restrict__ htb1, ushort_t* __restrict__ wc2,
    ushort_t* __restrict__ wc3, ushort_t* __restrict__ wAp,
    float* __restrict__ l0bp, ushort_t* __restrict__ whid,
    ushort_t* __restrict__ wt2, float* __restrict__ bhid) {
  if (blockIdx.x < 1989) {
    // ---- weight prep ----
    int i = blockIdx.x * 256 + threadIdx.x;
    if (i < 18432) {  // conv2 w -> [oc][kt][ic] bf16
      int oc = i / 288, r = i % 288, kt = r / 32, ic = r % 32;
      wc2[i] = f2bf(conv2_w[((oc * 32 + ic) * 3 + kt / 3) * 3 + kt % 3]);
      return;
    }
    i -= 18432;
    if (i < 36864) {  // conv3 w -> [oc][c][kt][ic] bf16
      int oc = i / 576, r = i % 576, c = r / 288, r2 = r % 288;
      int kt = r2 / 32, icl = r2 % 32, ic = c * 32 + icl;
      wc3[i] = f2bf(conv3_w[((oc * 64 + ic) * 3 + kt / 3) * 3 + kt % 3]);
      return;
    }
    i -= 36864;
    if (i < 98304) {  // W' = wih0[:, :128] @ projW, permuted + gate-scaled
      int n = i / 192, k = i % 192;
      int src = gperm(n);
      float a = 0.f;
      if (k < 160) {
        const float* wr = wih0 + src * 192;
        for (int j = 0; j < 128; ++j) a = fmaf(wr[j], projW[j * 160 + k], a);
      }
      wAp[i] = f2bf(a * gsc(n & 3));
      return;
    }
    i -= 98304;
    if (i < 512) {  // l0b' = l0_b + wih0[:, :128] @ proj_b, permuted + scaled
      int src = gperm(i);
      float a = l0_b[src];
      const float* wr = wih0 + src * 192;
      for (int j = 0; j < 128; ++j) a = fmaf(wr[j], projb[j], a);
      l0bp[i] = a * gsc(i & 3);
      return;
    }
    i -= 512;
    if (i < 98304) {  // concat head hidden weights
      int row = i >> 7, c = i & 127;
      float v = (row < 256)   ? hbw1[row * 128 + c]
                : (row < 512) ? hcw1[(row - 256) * 128 + c]
                              : htw1[(row - 512) * 128 + c];
      whid[i] = f2bf(v);
      return;
    }
    i -= 98304;
    if (i < 256000) {
      wt2[i] = f2bf(htw2[i]);
      return;
    }
    i -= 256000;
    if (i < 768)
      bhid[i] = (i < 256) ? hbb1[i] : (i < 512) ? hcb1[i - 256] : htb1[i - 512];
    return;
  }
  int bx = blockIdx.x - 1989;
  if (bx < 14400) {
    // ---- conv1: 2->32, naive, fused BN+ReLU, bf16 out ----
    int idx = bx * 256 + threadIdx.x;
    int x = idx % 60;
    int y = (idx / 60) % 60;
    int oc = (idx / 3600) % 32;
    int b = idx / (3600 * 32);
    float acc = 0.f;
#pragma unroll
    for (int ic = 0; ic < 2; ++ic) {
      const float* src = mv + (b * 2 + ic) * NPIX;
      const float* wp = c1w + (oc * 2 + ic) * 9;
#pragma unroll
      for (int ky = 0; ky < 3; ++ky) {
        int gy = y + ky - 1;
        if (gy < 0 || gy >= 60) continue;
#pragma unroll
        for (int kx = 0; kx < 3; ++kx) {
          int gx = x + kx - 1;
          if (gx < 0 || gx >= 60) continue;
          acc = fmaf(src[gy * 60 + gx], wp[ky * 3 + kx], acc);
        }
      }
    }
    float s = bg1[oc] * rsqrtf(1.f + 1e-5f);
    float v = fmaf(acc, s, fmaf(c1b[oc], s, bb1[oc]));
    x1out[idx] = f2bf(fmaxf(v, 0.f));
    return;
  }
  // ---- box stats + small MLPs: 2 boxes per block ----
  __shared__ float obj[2][160];
  __shared__ float hm[2][32];
  __shared__ float hbx[2][32];
  __shared__ float stats[2][8];
  __shared__ float boxf[2][4];
  __shared__ float red[2][2][8];
  int h = threadIdx.x >> 7;
  int t = threadIdx.x & 127;
  int blk = (bx - 14400) * 2 + h;  // box index 0..9599
  int b = blk / 300;
  float bx0 = boxes[blk * 4 + 0], by0 = boxes[blk * 4 + 1];
  float bx1 = boxes[blk * 4 + 2], by1 = boxes[blk * 4 + 3];
  const float HI = (float)(60.0 - 1e-6);
  float gx1 = fminf(fmaxf(bx0 * 60.f, 0.f), HI);
  float gy1 = fminf(fmaxf(by0 * 60.f, 0.f), HI);
  float gx2 = fminf(fmaxf(bx1 * 60.f, 0.f), HI);
  float gy2 = fminf(fmaxf(by1 * 60.f, 0.f), HI);
  float fx1 = floorf(gx1), fy1 = floorf(gy1);
  float fx2 = fmaxf(fx1 + 1.f, ceilf(gx2));
  float fy2 = fmaxf(fy1 + 1.f, ceilf(gy2));
  int ix1 = (int)fx1, iy1 = (int)fy1, ix2 = (int)fx2, iy2 = (int)fy2;
  int w = ix2 - ix1, hgt = iy2 - iy1;
  int area = w * hgt;
  float s0 = 0.f, s1 = 0.f, q0 = 0.f, q1 = 0.f;
  float mn0 = 1e9f, mn1 = 1e9f, mx0 = -1e9f, mx1 = -1e9f;
  const float* mv0 = mv + b * 2 * NPIX;
  const float* mv1 = mv0 + NPIX;
  for (int i = t; i < area; i += 128) {
    int r = i / w, cc = i - r * w;
    int yy = iy1 + r, xx = ix1 + cc;
    float v0 = mv0[yy * 60 + xx];
    float v1 = mv1[yy * 60 + xx];
    s0 += v0; q0 += v0 * v0; mn0 = fminf(mn0, v0); mx0 = fmaxf(mx0, v0);
    s1 += v1; q1 += v1 * v1; mn1 = fminf(mn1, v1); mx1 = fmaxf(mx1, v1);
  }
#pragma unroll
  for (int off = 32; off; off >>= 1) {
    s0 += __shfl_down(s0, off); s1 += __shfl_down(s1, off);
    q0 += __shfl_down(q0, off); q1 += __shfl_down(q1, off);
    mn0 = fminf(mn0, __shfl_down(mn0, off));
    mn1 = fminf(mn1, __shfl_down(mn1, off));
    mx0 = fmaxf(mx0, __shfl_down(mx0, off));
    mx1 = fmaxf(mx1, __shfl_down(mx1, off));
  }
  if ((t & 63) == 0) {
    int wv = t >> 6;
    red[h][wv][0] = s0; red[h][wv][1] = s1;
    red[h][wv][2] = q0; red[h][wv][3] = q1;
    red[h][wv][4] = mn0; red[h][wv][5] = mn1;
    red[h][wv][6] = mx0; red[h][wv][7] = mx1;
  }
  __syncthreads();
  if (t == 0) {
    float S0 = red[h][0][0] + red[h][1][0], S1 = red[h][0][1] + red[h][1][1];
    float Q0 = red[h][0][2] + red[h][1][2], Q1 = red[h][0][3] + red[h][1][3];
    float MN0 = fminf(red[h][0][4], red[h][1][4]);
    float MN1 = fminf(red[h][0][5], red[h][1][5]);
    float MX0 = fmaxf(red[h][0][6], red[h][1][6]);
    float MX1 = fmaxf(red[h][0][7], red[h][1][7]);
    float cnt = (float)area;
    float mean0 = S0 / cnt, mean1 = S1 / cnt;
    float var0 = (Q0 - cnt * mean0 * mean0) / fmaxf(cnt - 1.f, 1.f);
    float var1 = (Q1 - cnt * mean1 * mean1) / fmaxf(cnt - 1.f, 1.f);
    float sd0 = (cnt > 1.f) ? sqrtf(fmaxf(var0, 1e-12f)) : 0.f;
    float sd1 = (cnt > 1.f) ? sqrtf(fmaxf(var1, 1e-12f)) : 0.f;
    stats[h][0] = mean0; stats[h][1] = mean1; stats[h][2] = sd0;
    stats[h][3] = sd1; stats[h][4] = MN0; stats[h][5] = MX0;
    stats[h][6] = MN1; stats[h][7] = MX1;
    boxf[h][0] = bx0; boxf[h][1] = by0; boxf[h][2] = bx1; boxf[h][3] = by1;
  }
  __syncthreads();
  if (t < 32) {
    float a = agg_b1[t];
#pragma unroll
    for (int k = 0; k < 8; ++k) a = fmaf(stats[h][k], agg_w1[t * 8 + k], a);
    hm[h][t] = fmaxf(a, 0.f);
  } else if (t < 64) {
    int j = t - 32;
    float a = bx_b1[j];
#pragma unroll
    for (int k = 0; k < 4; ++k) a = fmaf(boxf[h][k], bx_w1[j * 4 + k], a);
    hbx[h][j] = fmaxf(a, 0.f);
  }
  __syncthreads();
  if (t < 64) {
    float a = bx_b2[t];
#pragma unroll
    for (int k = 0; k < 32; ++k) a = fmaf(hbx[h][k], bx_w2[t * 32 + k], a);
    obj[h][t] = a;
  } else {
    int j = t - 64;
    float a = agg_b2[j];
#pragma unroll
    for (int k = 0; k < 32; ++k) a = fmaf(hm[h][k], agg_w2[j * 32 + k], a);
    obj[h][96 + j] = a;
  }
  if (t < 32) {
    int id = ids[blk];
    id = min(max(id, 0), 999);
    obj[h][64 + t] = id_table[id * 32 + t];
  }
  __syncthreads();
  obj_out[(size_t)blk * 192 + t] = f2bf(obj[h][t]);
  if (t < 32) {
    obj_out[(size_t)blk * 192 + 128 + t] = f2bf(obj[h][128 + t]);
    obj_out[(size_t)blk * 192 + 160 + t] = 0;
  }
}

// ---------------- conv2/conv3: MFMA implicit-GEMM, pre-laid-out bf16 w ------
template <int CIN, bool POOL>
__global__ __launch_bounds__(256) void conv_mfma_kernel(
    const ushort_t* __restrict__ in, const ushort_t* __restrict__ wc,
    const float* __restrict__ cb, const float* __restrict__ bg,
    const float* __restrict__ bb, ushort_t* __restrict__ out,
    float* __restrict__ gf) {
  constexpr int NCHUNK = CIN / 32;
  __shared__ ushort_t in_lds[18 * 18 * 40];
  int tid = threadIdx.x;
  int wv = tid >> 6, lane = tid & 63;
  int col = lane & 15, kg = lane >> 4;
  int b = blockIdx.y, tile = blockIdx.x;
  int tq = tile >> 2, tr = tile & 3;
  int ty0 = tq * 16 - (tq == 3 ? 4 : 0);
  int tx0 = tr * 16 - (tr == 3 ? 4 : 0);
  int oc = wv * 16 + col;

  bf16x8 bw[NCHUNK * 9];
#pragma unroll
  for (int c = 0; c < NCHUNK; ++c)
#pragma unroll
    for (int kt = 0; kt < 9; ++kt)
      bw[c * 9 + kt] = *(const bf16x8*)(wc + oc * (NCHUNK * 288) + c * 288 +
                                        kt * 32 + kg * 8);

  f32x4 acc[16];
#pragma unroll
  for (int m = 0; m < 16; ++m) acc[m] = (f32x4){0.f, 0.f, 0.f, 0.f};

  for (int c = 0; c < NCHUNK; ++c) {
    if (c) __syncthreads();
    for (int i = tid; i < 18 * 18 * 32; i += 256) {
      int ic = i / 324, rem = i % 324;
      int yy = rem / 18, xx = rem % 18;
      int gy = ty0 + yy - 1, gx = tx0 + xx - 1;
      ushort_t v = 0;
      if (gy >= 0 && gy < 60 && gx >= 0 && gx < 60)
        v = in[((size_t)(b * CIN + c * 32 + ic) * 60 + gy) * 60 + gx];
      in_lds[(yy * 18 + xx) * 40 + ic] = v;
    }
    __syncthreads();
#pragma unroll
    for (int kt = 0; kt < 9; ++kt) {
      int ky = kt / 3, kx = kt % 3;
#pragma unroll
      for (int m = 0; m < 16; ++m) {
        bf16x8 af =
            *(const bf16x8*)(&in_lds[((m + ky) * 18 + col + kx) * 40 + kg * 8]);
        acc[m] = __builtin_amdgcn_mfma_f32_16x16x32_bf16(af, bw[c * 9 + kt],
                                                         acc[m], 0, 0, 0);
      }
    }
  }
  float s = bg[oc] * rsqrtf(1.f + 1e-5f);
  float bias = fmaf(cb[oc], s, bb[oc]);
  float pool = 0.f;
#pragma unroll
  for (int m = 0; m < 16; ++m) {
    float vv[4];
#pragma unroll
    for (int r = 0; r < 4; ++r) vv[r] = fmaxf(fmaf(acc[m][r], s, bias), 0.f);
    if (POOL) {
      bool ymask = (tq != 3) || (m >= 4);
#pragma unroll
      for (int r = 0; r < 4; ++r) {
        int px = kg * 4 + r;
        bool xmask = (tr != 3) || (px >= 4);
        if (ymask && xmask) pool += vv[r];
      }
    } else {
      ushort_t st[4];
#pragma unroll
      for (int r = 0; r < 4; ++r) st[r] = f2bf(vv[r]);
      int yy = ty0 + m, xx = tx0 + kg * 4;
      *(uint2*)(&out[((size_t)(b * 64 + oc) * 60 + yy) * 60 + xx]) =
          *(uint2*)st;
    }
  }
  if (POOL) {
    pool += __shfl_xor(pool, 16);
    pool += __shfl_xor(pool, 32);
    if (lane < 16) atomicAdd(&gf[b * 64 + oc], pool);
  }
}

// ---------------- bf16-W MFMA GEMM: C = act(A@W^T + b [+ gvec]) -------------
template <int ACT, bool OBF16, bool GVEC>
__global__ __launch_bounds__(256) void gemm_bf16w_kernel(
    const ushort_t* __restrict__ A, int lda, const ushort_t* __restrict__ W,
    const float* __restrict__ bias, void* __restrict__ C, int ldc, int M,
    int N, int K, const float* __restrict__ gvec) {
  __shared__ ushort_t As[128 * 64];
  __shared__ ushort_t Ws[64 * 64];
  int tid = threadIdx.x;
  int wv = tid >> 6, lane = tid & 63;
  int col = lane & 15, kg = lane >> 4;
  int wm = wv >> 1, wn = wv & 1;
  int m0 = blockIdx.x * 128, n0 = blockIdx.y * 64;
  f32x4 acc[4][2];
#pragma unroll
  for (int i = 0; i < 4; ++i)
#pragma unroll
    for (int j = 0; j < 2; ++j) acc[i][j] = (f32x4){0.f, 0.f, 0.f, 0.f};

  int nk = K >> 6;
  for (int kc = 0; kc < nk; ++kc) {
    if (kc) __syncthreads();
#pragma unroll
    for (int q = 0; q < 4; ++q) {
      int idx = q * 256 + tid;
      int row = idx >> 3, ch = idx & 7;
      uint4 v =
          *(const uint4*)(A + (size_t)(m0 + row) * lda + kc * 64 + ch * 8);
      *(uint4*)(&As[row * 64 + ((ch * 8) ^ ((row & 7) << 3))]) = v;
    }
#pragma unroll
    for (int q = 0; q < 2; ++q) {
      int idx = q * 256 + tid;
      int row = idx >> 3, ch = idx & 7;
      int n = n0 + row;
      uint4 v = make_uint4(0, 0, 0, 0);
      if (n < N) v = *(const uint4*)(W + (size_t)n * K + kc * 64 + ch * 8);
      *(uint4*)(&Ws[row * 64 + ((ch * 8) ^ ((row & 7) << 3))]) = v;
    }
    __syncthreads();
#pragma unroll
    for (int ks = 0; ks < 2; ++ks) {
      bf16x8 bfr[2], afr[4];
#pragma unroll
      for (int ni = 0; ni < 2; ++ni) {
        int row = wn * 32 + ni * 16 + col;
        bfr[ni] = *(const bf16x8*)(
            &Ws[row * 64 + ((ks * 32 + kg * 8) ^ ((row & 7) << 3))]);
      }
#pragma unroll
      for (int mi = 0; mi < 4; ++mi) {
        int row = wm * 64 + mi * 16 + col;
        afr[mi] = *(const bf16x8*)(
            &As[row * 64 + ((ks * 32 + kg * 8) ^ ((row & 7) << 3))]);
      }
#pragma unroll
      for (int mi = 0; mi < 4; ++mi)
#pragma unroll
        for (int ni = 0; ni < 2; ++ni)
          acc[mi][ni] = __builtin_amdgcn_mfma_f32_16x16x32_bf16(
              afr[mi], bfr[ni], acc[mi][ni], 0, 0, 0);
    }
  }
#pragma unroll
  for (int ni = 0; ni < 2; ++ni) {
    int n = n0 + wn * 32 + ni * 16 + col;
    float bn = (n < N) ? bias[n] : 0.f;
#pragma unroll
    for (int mi = 0; mi < 4; ++mi) {
      int mbase = m0 + wm * 64 + mi * 16 + kg * 4;
#pragma unroll
      for (int r = 0; r < 4; ++r) {
        float v = acc[mi][ni][r] + bn;
        if (GVEC) v += gvec[((mbase + r) / 300) * 512 + n];
        if (ACT == 1) v = fmaxf(v, 0.f);
        if (n < N) {
          if (OBF16)
            ((ushort_t*)C)[(size_t)(mbase + r) * ldc + n] = f2bf(v);
          else
            ((float*)C)[(size_t)(mbase + r) * ldc + n] = v;
        }
      }
    }
  }
}

// ---------------- fused pipelined 2-layer LSTM scan (= v9 core) --------------
// 8 waves/block, 1 cell/lane, ONE barrier/step. v10's in-kernel tail
// consumers REVERTED: their streaming L2/HBM traffic on the producer XCDs
// slowed the latency-bound scan by +43% (300->429us) — more than the serial
// tail they hid. Tail now runs as a standalone fused kernel after this one.
#define LSTM_BAR() asm volatile("s_waitcnt lgkmcnt(0)\n\ts_barrier" ::: "memory")

__global__ __launch_bounds__(512) void lstm_fused_kernel(
    const float* __restrict__ pre0,  // [32][300][512] f32, permuted+scaled
    const float* __restrict__ whh0,  // [512,128]
    const float* __restrict__ wih1,  // [512,128]
    const float* __restrict__ whh1,  // [512,128]
    const float* __restrict__ b1,    // [512]
    float* __restrict__ pre1,        // [32][300][512] f32, permuted+scaled
    ushort_t* __restrict__ y0,       // [32][300][128] bf16 (L0 -> u)
    ushort_t* __restrict__ y1,       // [32][300][128] bf16
    float* __restrict__ outH, float* __restrict__ outC,
    unsigned int* __restrict__ flags)  // [8*32] padded
{
  __shared__ ushort_t h_lds[2][4][160];
  int tid = threadIdx.x;
  int w = tid >> 6, lane = tid & 63;
  int col = lane & 15, kg = lane >> 4;
  int bat = col & 3, q = col >> 2;
  int cell = (4 * w + q) * 4 + kg;
  float wsc = gsc(col & 3);  // A-row = col -> gate = col&3

  if (blockIdx.x < 8) {
    // ---------------- layer 0 ----------------
    int g = blockIdx.x;
    int b0 = g * 4;
    unsigned int* flagp = &flags[g * 32];
    for (int i = tid; i < 2 * 4 * 160; i += 512) ((ushort_t*)h_lds)[i] = 0;
    bf16x8 aW0[4][4];
#pragma unroll
    for (int j = 0; j < 4; ++j) {
      int rho = (4 * w + j) * 16 + col;
      int src = gperm(rho);
#pragma unroll
      for (int kt = 0; kt < 4; ++kt) {
        const float* s1 = whh0 + src * 128 + kt * 32 + kg * 8;
        bf16x8 f1;
#pragma unroll
        for (int qq = 0; qq < 8; ++qq) f1[qq] = (short)f2bf(s1[qq] * wsc);
        aW0[j][kt] = f1;
      }
    }
    const float* pg = pre0 + (size_t)(b0 + bat) * 300 * 512 + 4 * cell;
    ushort_t* yg0 = y0 + ((size_t)(b0 + bat) * 300) * 128 + cell;
    float c = 0.f, hout = 0.f;
    f32x4 p0v = *(const f32x4*)(pg);
    f32x4 p1v = *(const f32x4*)(pg + 512);
    __syncthreads();

    for (int s = 0; s < 300; ++s) {
      const ushort_t* hb = h_lds[s & 1][bat];
      bf16x8 bfr[4];
#pragma unroll
      for (int kt = 0; kt < 4; ++kt)
        bfr[kt] = *(const bf16x8*)(hb + kt * 32 + kg * 8);
      f32x4 a0 = {0.f, 0.f, 0.f, 0.f}, a1 = a0, a2 = a0, a3 = a0;
#pragma unroll
      for (int kt = 0; kt < 4; ++kt) {
        a0 = __builtin_amdgcn_mfma_f32_16x16x32_bf16(aW0[0][kt], bfr[kt], a0, 0, 0, 0);
        a1 = __builtin_amdgcn_mfma_f32_16x16x32_bf16(aW0[1][kt], bfr[kt], a1, 0, 0, 0);
        a2 = __builtin_amdgcn_mfma_f32_16x16x32_bf16(aW0[2][kt], bfr[kt], a2, 0, 0, 0);
        a3 = __builtin_amdgcn_mfma_f32_16x16x32_bf16(aW0[3][kt], bfr[kt], a3, 0, 0, 0);
      }
      // static select of own tile (q uniform per lane; cndmask, no scratch)
      f32x4 z = a0;
      if (q == 1) z = a1;
      if (q == 2) z = a2;
      if (q == 3) z = a3;
      {
        float zi = z[0] + p0v[0];
        float zf = z[1] + p0v[1];
        float zg = z[2] + p0v[2];
        float zo = z[3] + p0v[3];
        float vi = __builtin_amdgcn_rcpf(1.f + __builtin_amdgcn_exp2f(-zi));
        float vf = __builtin_amdgcn_rcpf(1.f + __builtin_amdgcn_exp2f(-zf));
        float vg = 1.f - 2.f * __builtin_amdgcn_rcpf(
                              __builtin_amdgcn_exp2f(zg) + 1.f);
        float vo = __builtin_amdgcn_rcpf(1.f + __builtin_amdgcn_exp2f(-zo));
        c = vf * c + vi * vg;
        hout = vo * (1.f - 2.f * __builtin_amdgcn_rcpf(
                             __builtin_amdgcn_exp2f(2.f * LOG2E * c) + 1.f));
        ushort_t hv = f2bf(hout);
        h_lds[(s + 1) & 1][bat][cell] = hv;
        __builtin_nontemporal_store(hv, yg0 + (size_t)s * 128);
        p0v = p1v;
        int sn = (s + 2 < 300) ? s + 2 : 299;
        p1v = *(const f32x4*)(pg + (size_t)sn * 512);
      }
      // 2 vmem ops/step; vmcnt(6) = 3 steps in flight => y0(<=s-3) retired
      asm volatile("s_waitcnt vmcnt(6)" ::: "memory");
      LSTM_BAR();
      if (tid == 0 && s >= 3)
        __hip_atomic_store(flagp, (unsigned int)(s - 3), __ATOMIC_RELAXED,
                           __HIP_MEMORY_SCOPE_AGENT);
    }
    asm volatile("s_waitcnt vmcnt(0)" ::: "memory");
    __syncthreads();
    if (tid == 0)
      __hip_atomic_store(flagp, 300u, __ATOMIC_RELAXED,
                         __HIP_MEMORY_SCOPE_AGENT);
    outH[(b0 + bat) * 128 + cell] = hout;
    outC[(b0 + bat) * 128 + cell] = c;
  } else if (blockIdx.x < 16) {
    // ---------------- layer 1 (mirror of L0, p from pre1 via u-flag) --------
    int g = blockIdx.x - 8;
    int b0 = g * 4;
    unsigned int* flagp = &flags[g * 32 + 16];
    for (int i = tid; i < 2 * 4 * 160; i += 512) ((ushort_t*)h_lds)[i] = 0;
    bf16x8 aW[4][4];
#pragma unroll
    for (int j = 0; j < 4; ++j) {
      int rho = (4 * w + j) * 16 + col;
      int src = gperm(rho);
#pragma unroll
      for (int kt = 0; kt < 4; ++kt) {
        const float* s1 = whh1 + src * 128 + kt * 32 + kg * 8;
        bf16x8 f1;
#pragma unroll
        for (int qq = 0; qq < 8; ++qq) f1[qq] = (short)f2bf(s1[qq] * wsc);
        aW[j][kt] = f1;
      }
    }
    float bi = b1[cell] * LOG2E, bff = b1[128 + cell] * LOG2E;
    float bgg = b1[256 + cell] * (2.f * LOG2E), boo = b1[384 + cell] * LOG2E;
    const float* pg = pre1 + (size_t)(b0 + bat) * 300 * 512 + 4 * cell;
    ushort_t* yg = y1 + (size_t)(b0 + bat) * 300 * 128 + cell;
    float c = 0.f, hout = 0.f;
    unsigned int fc = 0;
    f32x4 p0v, p1v;
    do {
      fc = __hip_atomic_load(flagp, __ATOMIC_RELAXED,
                             __HIP_MEMORY_SCOPE_AGENT);
      if (fc < 1) __builtin_amdgcn_s_sleep(2);
    } while (fc < 1);
    asm volatile("" ::: "memory");
    p0v = __builtin_nontemporal_load((const f32x4*)(pg));
    while (fc < 2) {
      fc = __hip_atomic_load(flagp, __ATOMIC_RELAXED,
                             __HIP_MEMORY_SCOPE_AGENT);
      if (fc < 2) __builtin_amdgcn_s_sleep(2);
    }
    asm volatile("" ::: "memory");
    p1v = __builtin_nontemporal_load((const f32x4*)(pg + 512));
    __syncthreads();

    for (int t = 0; t < 300; ++t) {
      // eager flag read: issue now, consume at the prefetch point below
      unsigned int fcn = __hip_atomic_load(flagp, __ATOMIC_RELAXED,
                                           __HIP_MEMORY_SCOPE_AGENT);
      const ushort_t* hb = h_lds[t & 1][bat];
      bf16x8 bfr[4];
#pragma unroll
      for (int kt = 0; kt < 4; ++kt)
        bfr[kt] = *(const bf16x8*)(hb + kt * 32 + kg * 8);
      f32x4 a0 = {0.f, 0.f, 0.f, 0.f}, a1 = a0, a2 = a0, a3 = a0;
#pragma unroll
      for (int kt = 0; kt < 4; ++kt) {
        a0 = __builtin_amdgcn_mfma_f32_16x16x32_bf16(aW[0][kt], bfr[kt], a0, 0, 0, 0);
        a1 = __builtin_amdgcn_mfma_f32_16x16x32_bf16(aW[1][kt], bfr[kt], a1, 0, 0, 0);
        a2 = __builtin_amdgcn_mfma_f32_16x16x32_bf16(aW[2][kt], bfr[kt], a2, 0, 0, 0);
        a3 = __builtin_amdgcn_mfma_f32_16x16x32_bf16(aW[3][kt], bfr[kt], a3, 0, 0, 0);
      }
      f32x4 z = a0;
      if (q == 1) z = a1;
      if (q == 2) z = a2;
      if (q == 3) z = a3;
      {
        float zi = z[0] + p0v[0] + bi;
        float zf = z[1] + p0v[1] + bff;
        float zg = z[2] + p0v[2] + bgg;
        float zo = z[3] + p0v[3] + boo;
        float vi = __builtin_amdgcn_rcpf(1.f + __builtin_amdgcn_exp2f(-zi));
        float vf = __builtin_amdgcn_rcpf(1.f + __builtin_amdgcn_exp2f(-zf));
        float vg = 1.f - 2.f * __builtin_amdgcn_rcpf(
                              __builtin_amdgcn_exp2f(zg) + 1.f);
        float vo = __builtin_amdgcn_rcpf(1.f + __builtin_amdgcn_exp2f(-zo));
        c = vf * c + vi * vg;
        hout = vo * (1.f - 2.f * __builtin_amdgcn_rcpf(
                             __builtin_amdgcn_exp2f(2.f * LOG2E * c) + 1.f));
        ushort_t hv = f2bf(hout);
        h_lds[(t + 1) & 1][bat][cell] = hv;
        yg[(size_t)t * 128] = hv;
        p0v = p1v;
        if (t + 2 < 300) {
          unsigned int need = (unsigned int)(t + 3);
          if (fcn > fc) fc = fcn;
          if (fc < need) {
            do {
              fc = __hip_atomic_load(flagp, __ATOMIC_RELAXED,
                                     __HIP_MEMORY_SCOPE_AGENT);
              if (fc < need) __builtin_amdgcn_s_sleep(2);
            } while (fc < need);
            asm volatile("" ::: "memory");
          }
          p1v = __builtin_nontemporal_load(
              (const f32x4*)(pg + (size_t)(t + 2) * 512));
        }
      }
      LSTM_BAR();
    }
    outH[4096 + (b0 + bat) * 128 + cell] = hout;
    outC[4096 + (b0 + bat) * 128 + cell] = c;
  } else {
    // ---------------- u-blocks: pre1[t] = Wih1 @ y0[t], 12-step chunks ------
    int g = blockIdx.x - 16;
    int b0 = g * 4;
    unsigned int* flag0 = &flags[g * 32];
    unsigned int* flag1 = &flags[g * 32 + 16];
    bf16x8 aU[4][4];
#pragma unroll
    for (int j = 0; j < 4; ++j) {
      int rho = (4 * w + j) * 16 + col;
      int src = gperm(rho);
#pragma unroll
      for (int kt = 0; kt < 4; ++kt) {
        const float* s2 = wih1 + src * 128 + kt * 32 + kg * 8;
        bf16x8 f2;
#pragma unroll
        for (int qq = 0; qq < 8; ++qq) f2[qq] = (short)f2bf(s2[qq] * wsc);
        aU[j][kt] = f2;
      }
    }
    int bb = col & 3;   // batch within group (B-col -> (batch, step))
    int ts = col >> 2;  // step within 4-step col-tile
    const ushort_t* yb = y0 + ((size_t)(b0 + bb) * 300) * 128 + kg * 8;
    unsigned int fc = 0;
    for (int t0 = 0; t0 < 300; t0 += 12) {
      unsigned int need = (unsigned int)(t0 + 11);
      while (fc < need) {
        fc = __hip_atomic_load(flag0, __ATOMIC_RELAXED,
                               __HIP_MEMORY_SCOPE_AGENT);
        if (fc < need) __builtin_amdgcn_s_sleep(2);
      }
      asm volatile("" ::: "memory");
      f32x4 acc[4][3];
#pragma unroll
      for (int j = 0; j < 4; ++j)
#pragma unroll
        for (int ct = 0; ct < 3; ++ct) acc[j][ct] = (f32x4){0.f, 0.f, 0.f, 0.f};
#pragma unroll
      for (int ct = 0; ct < 3; ++ct) {
        int t = t0 + ct * 4 + ts;
        bf16x8 bfr[4];
#pragma unroll
        for (int kt = 0; kt < 4; ++kt)
          bfr[kt] = __builtin_nontemporal_load(
              (const bf16x8*)(yb + (size_t)t * 128 + kt * 32));
#pragma unroll
        for (int kt = 0; kt < 4; ++kt) {
          acc[0][ct] = __builtin_amdgcn_mfma_f32_16x16x32_bf16(aU[0][kt], bfr[kt], acc[0][ct], 0, 0, 0);
          acc[1][ct] = __builtin_amdgcn_mfma_f32_16x16x32_bf16(aU[1][kt], bfr[kt], acc[1][ct], 0, 0, 0);
          acc[2][ct] = __builtin_amdgcn_mfma_f32_16x16x32_bf16(aU[2][kt], bfr[kt], acc[2][ct], 0, 0, 0);
          acc[3][ct] = __builtin_amdgcn_mfma_f32_16x16x32_bf16(aU[3][kt], bfr[kt], acc[3][ct], 0, 0, 0);
        }
      }
#pragma unroll
      for (int ct = 0; ct < 3; ++ct) {
        int t = t0 + ct * 4 + ts;
        float* pd = pre1 + ((size_t)(b0 + bb) * 300 + t) * 512 + kg * 4;
#pragma unroll
        for (int j = 0; j < 4; ++j)
          __builtin_nontemporal_store(acc[j][ct],
                                      (f32x4*)(pd + (4 * w + j) * 16));
      }
      asm volatile("s_waitcnt vmcnt(0)" ::: "memory");
      __syncthreads();
      if (tid == 0)
        __hip_atomic_store(flag1, (unsigned int)(t0 + 12), __ATOMIC_RELAXED,
                           __HIP_MEMORY_SCOPE_AGENT);
    }
  }
}

// ---------- standalone fused tail: hid GEMM + heads + tid GEMM --------------
// Same (correctness-verified in v10) per-chunk logic, run AFTER the scan so
// its streaming traffic can't contend with the latency-bound LSTM. Block
// (g,ck): 120 rows = 4 batches x 30 steps. hid scratch = pre0 region (dead).
// One dispatch replaces three (gemm_hid, head_small, gemm_tid).
__global__ __launch_bounds__(512) void tail_kernel(
    const ushort_t* __restrict__ y1, ushort_t* __restrict__ hid16,
    const ushort_t* __restrict__ whid, const ushort_t* __restrict__ wt2,
    const float* __restrict__ bhid, const float* __restrict__ hbw2,
    const float* __restrict__ hbb2, const float* __restrict__ hcw2,
    const float* __restrict__ hcb2, const float* __restrict__ htb2,
    float* __restrict__ outB, float* __restrict__ outCls,
    float* __restrict__ outT) {
  __shared__ ushort_t smem[30720];  // 61440 B union (As/Ws | As2)
  int tid = threadIdx.x;
  int w = tid >> 6, lane = tid & 63;
  int col = lane & 15, kg = lane >> 4;
  int g = blockIdx.x & 7, ck = blockIdx.x >> 3;
  int b0 = g * 4, t0 = ck * 30;
  int wm = w >> 2, wn = w & 3;
  int Rt[4][4];
  bool Vt[4][4];
#pragma unroll
  for (int mi = 0; mi < 4; ++mi)
#pragma unroll
    for (int r = 0; r < 4; ++r) {
      int m = wm * 64 + mi * 16 + kg * 4 + r;
      Vt[mi][r] = (m < 120);
      int mm = (m < 120) ? m : 119;
      Rt[mi][r] = (b0 + mm / 30) * 300 + t0 + mm % 30;
    }
  // ---- GEMM1: hid = relu(y1chunk @ whid^T + bhid) -> hid16 slots ----
  ushort_t* As = smem;          // [128][128]
  ushort_t* Wt = smem + 16384;  // [64][128]
  for (int i = tid; i < 2048; i += 512) {
    int r = i >> 4, ch = i & 15;
    uint4 v = make_uint4(0, 0, 0, 0);
    if (r < 120) {
      int R = (b0 + r / 30) * 300 + t0 + r % 30;
      v = *(const uint4*)(y1 + (size_t)R * 128 + ch * 8);
    }
    *(uint4*)(&As[r * 128 + ((ch * 8) ^ ((r & 7) << 3))]) = v;
  }
  __syncthreads();
  for (int nt = 0; nt < 12; ++nt) {
    if (nt) __syncthreads();
    for (int i = tid; i < 1024; i += 512) {
      int r = i >> 4, ch = i & 15;
      uint4 v = *(const uint4*)(whid + (size_t)(nt * 64 + r) * 128 + ch * 8);
      *(uint4*)(&Wt[r * 128 + ((ch * 8) ^ ((r & 7) << 3))]) = v;
    }
    __syncthreads();
    f32x4 acc[4];
#pragma unroll
    for (int mi = 0; mi < 4; ++mi) acc[mi] = (f32x4){0.f, 0.f, 0.f, 0.f};
    int rl = wn * 16 + col;
#pragma unroll
    for (int ks = 0; ks < 4; ++ks) {
      bf16x8 bfr = *(const bf16x8*)(
          &Wt[rl * 128 + ((ks * 32 + kg * 8) ^ ((rl & 7) << 3))]);
#pragma unroll
      for (int mi = 0; mi < 4; ++mi) {
        int rm = wm * 64 + mi * 16 + col;
        bf16x8 afr = *(const bf16x8*)(
            &As[rm * 128 + ((ks * 32 + kg * 8) ^ ((rm & 7) << 3))]);
        acc[mi] = __builtin_amdgcn_mfma_f32_16x16x32_bf16(afr, bfr, acc[mi],
                                                          0, 0, 0);
      }
    }
    int n = nt * 64 + wn * 16 + col;
    float bn = bhid[n];
#pragma unroll
    for (int mi = 0; mi < 4; ++mi)
#pragma unroll
      for (int r = 0; r < 4; ++r)
        if (Vt[mi][r]) {
          float v = fmaxf(acc[mi][r] + bn, 0.f);
          hid16[(size_t)Rt[mi][r] * 1024 + n] = f2bf(v);
        }
  }
  asm volatile("s_waitcnt vmcnt(0)" ::: "memory");
  __syncthreads();
  // ---- small heads (B: sigmoid x4, C: x2) ----
  for (int o = tid; o < 720; o += 512) {
    int m = o / 6, j = o % 6;
    int R = (b0 + m / 30) * 300 + t0 + m % 30;
    const ushort_t* hsrc = hid16 + (size_t)R * 1024 + (j < 4 ? 0 : 256);
    const float* wrow = (j < 4) ? hbw2 + j * 256 : hcw2 + (j - 4) * 256;
    float a = (j < 4) ? hbb2[j] : hcb2[j - 4];
    for (int k = 0; k < 256; k += 8) {
      uint4 hv = *(const uint4*)(hsrc + k);
      unsigned int wq[4] = {hv.x, hv.y, hv.z, hv.w};
#pragma unroll
      for (int qq = 0; qq < 4; ++qq) {
        a = fmaf(bf2f((ushort_t)(wq[qq] & 0xffff)), wrow[k + 2 * qq], a);
        a = fmaf(bf2f((ushort_t)(wq[qq] >> 16)), wrow[k + 2 * qq + 1], a);
      }
    }
    if (j < 4) outB[R * 4 + j] = sigf(a);
    else outCls[R * 2 + (j - 4)] = a;
  }
  __syncthreads();
  // ---- GEMM2: outT = hid2 @ wt2^T + ht_b2 ----
  ushort_t* As2 = smem;  // [120][256]
  for (int i = tid; i < 3840; i += 512) {
    int r = i >> 5, ch = i & 31;
    int R = (b0 + r / 30) * 300 + t0 + r % 30;
    uint4 v = *(const uint4*)(hid16 + (size_t)R * 1024 + 512 + ch * 8);
    *(uint4*)(&As2[r * 256 + ((ch * 8) ^ ((r & 7) << 3))]) = v;
  }
  __syncthreads();
  for (int nt = 0; nt < 16; ++nt) {
    f32x4 acc[4];
#pragma unroll
    for (int mi = 0; mi < 4; ++mi) acc[mi] = (f32x4){0.f, 0.f, 0.f, 0.f};
    int n = nt * 64 + wn * 16 + col;
    int nc = (n < 1000) ? n : 999;
#pragma unroll
    for (int ks = 0; ks < 8; ++ks) {
      bf16x8 bfr = *(const bf16x8*)(wt2 + (size_t)nc * 256 + ks * 32 + kg * 8);
#pragma unroll
      for (int mi = 0; mi < 4; ++mi) {
        int rm = wm * 64 + mi * 16 + col;
        int rc = (rm < 120) ? rm : 119;
        bf16x8 afr = *(const bf16x8*)(
            &As2[rc * 256 + ((ks * 32 + kg * 8) ^ ((rc & 7) << 3))]);
        acc[mi] = __builtin_amdgcn_mfma_f32_16x16x32_bf16(afr, bfr, acc[mi],
                                                          0, 0, 0);
      }
    }
    float bn = htb2[nc];
    bool nok = (n < 1000);
#pragma unroll
    for (int mi = 0; mi < 4; ++mi)
#pragma unroll
      for (int r = 0; r < 4; ++r)
        if (Vt[mi][r] && nok)
          __builtin_nontemporal_store(
              acc[mi][r] + bn, &outT[(size_t)Rt[mi][r] * 1000 + n]);
  }
}

// ---------------- launch ----------------
extern "C" void kernel_launch(void* const* d_in, const int* in_sizes, int n_in,
                              void* d_out, int out_size, void* d_ws,
                              size_t ws_size, hipStream_t stream) {
  const float* mv = (const float*)d_in[0];
  const float* boxes = (const float*)d_in[1];
  const int* track_ids = (const int*)d_in[2];
  const float* conv1_w = (const float*)d_in[3];
  const float* conv1_b = (const float*)d_in[4];
  const float* bn1_g = (const float*)d_in[5];
  const float* bn1_b = (const float*)d_in[6];
  const float* conv2_w = (const float*)d_in[7];
  const float* conv2_b = (const float*)d_in[8];
  const float* bn2_g = (const float*)d_in[9];
  const float* bn2_b = (const float*)d_in[10];
  const float* conv3_w = (const float*)d_in[11];
  const float* conv3_b = (const float*)d_in[12];
  const float* bn3_g = (const float*)d_in[13];
  const float* bn3_b = (const float*)d_in[14];
  const float* agg_w1 = (const float*)d_in[15];
  const float* agg_b1 = (const float*)d_in[16];
  const float* agg_w2 = (const float*)d_in[17];
  const float* agg_b2 = (const float*)d_in[18];
  const float* bx_w1 = (const float*)d_in[19];
  const float* bx_b1 = (const float*)d_in[20];
  const float* bx_w2 = (const float*)d_in[21];
  const float* bx_b2 = (const float*)d_in[22];
  const float* id_table = (const float*)d_in[23];
  const float* proj_w = (const float*)d_in[24];
  const float* proj_b = (const float*)d_in[25];
  const float* l0_wih = (const float*)d_in[27];
  const float* l0_whh = (const float*)d_in[28];
  const float* l0_b = (const float*)d_in[29];
  const float* l1_wih = (const float*)d_in[30];
  const float* l1_whh = (const float*)d_in[31];
  const float* l1_b = (const float*)d_in[32];
  const float* hb_w1 = (const float*)d_in[33];
  const float* hb_b1 = (const float*)d_in[34];
  const float* hb_w2 = (const float*)d_in[35];
  const float* hb_b2 = (const float*)d_in[36];
  const float* hc_w1 = (const float*)d_in[37];
  const float* hc_b1 = (const float*)d_in[38];
  const float* hc_w2 = (const float*)d_in[39];
  const float* hc_b2 = (const float*)d_in[40];
  const float* ht_w1 = (const float*)d_in[41];
  const float* ht_b1 = (const float*)d_in[42];
  const float* ht_w2 = (const float*)d_in[43];
  const float* ht_b2 = (const float*)d_in[44];

  char* wsb = (char*)d_ws;
  ushort_t* x1u = (ushort_t*)(wsb + 0);          // 7,372,800 B
  ushort_t* x2u = (ushort_t*)(wsb + 7372800);    // 14,745,600 B
  float* pre0 = (float*)(wsb + 0);               // 19,660,800 B (alias convs;
                                                 // reused as hid after lstm)
  ushort_t* y0g = (ushort_t*)(wsb + 19660800);   // 2,457,600 B (x2u tail)
  float* gf = (float*)(wsb + 22118400);          // 8,192 B
  ushort_t* obj = (ushort_t*)(wsb + 22126592);   // 3,686,400 B
  float* pre1 = (float*)(wsb + 25812992);        // 19,660,800 B
  ushort_t* y1b = (ushort_t*)(wsb + 45473792);   // 2,457,600 B
  unsigned int* flags = (unsigned int*)(wsb + 47931392);  // 1,024 B
  ushort_t* wAp = (ushort_t*)(wsb + 47932416);   // 196,608 B
  ushort_t* whid = (ushort_t*)(wsb + 48129024);  // 196,608 B
  ushort_t* wt2 = (ushort_t*)(wsb + 48325632);   // 512,000 B
  float* bhid = (float*)(wsb + 48837632);        // 3,072 B
  float* l0bp = (float*)(wsb + 48840704);        // 2,048 B
  float* gvec = (float*)(wsb + 48842752);        // 65,536 B
  ushort_t* wc2 = (ushort_t*)(wsb + 48908288);   // 36,864 B
  ushort_t* wc3 = (ushort_t*)(wsb + 48945152);   // 73,728 B

  float* outB = (float*)d_out;    // [32,300,4]
  float* outC = outB + 38400;     // [32,300,2]
  float* outT = outB + 57600;     // [32,300,1000]
  float* outH = outB + 9657600;   // [2,32,128]
  float* outCc = outB + 9665792;  // [2,32,128]

  hipMemsetAsync(gf, 0, 2048 * sizeof(float), stream);
  hipMemsetAsync(flags, 0, 1024, stream);

  front_kernel<<<21189, 256, 0, stream>>>(
      mv, conv1_w, conv1_b, bn1_g, bn1_b, x1u, boxes, track_ids, agg_w1,
      agg_b1, agg_w2, agg_b2, bx_w1, bx_b1, bx_w2, bx_b2, id_table, obj,
      conv2_w, conv3_w, l0_wih, proj_w, proj_b, l0_b, hb_w1, hc_w1, ht_w1,
      ht_w2, hb_b1, hc_b1, ht_b1, wc2, wc3, wAp, l0bp, whid, wt2, bhid);
  conv_mfma_kernel<32, false><<<dim3(16, 32), 256, 0, stream>>>(
      x1u, wc2, conv2_b, bn2_g, bn2_b, x2u, nullptr);
  conv_mfma_kernel<64, true><<<dim3(16, 32), 256, 0, stream>>>(
      x2u, wc3, conv3_b, bn3_g, bn3_b, nullptr, gf);
  gvec_kernel<<<64, 256, 0, stream>>>(l0_wih, gf, gvec);
  gemm_bf16w_kernel<0, false, true><<<dim3(75, 8), 256, 0, stream>>>(
      obj, 192, wAp, l0bp, pre0, 512, 9600, 512, 192, gvec);
  lstm_fused_kernel<<<24, 512, 0, stream>>>(pre0, l0_whh, l1_wih, l1_whh,
                                            l1_b, pre1, y0g, y1b, outH, outCc,
                                            flags);
  tail_kernel<<<80, 512, 0, stream>>>(y1b, (ushort_t*)pre0, whid, wt2, bhid,
                                      hb_w2, hb_b2, hc_w2, hc_b2, ht_b2, outB,
                                      outC, outT);
}

// Round 8
// 472.444 us; speedup vs baseline: 1.3306x; 1.3227x over previous
//
#include <hip/hip_runtime.h>
#include <hip/hip_bf16.h>
#include <math.h>

typedef unsigned short ushort_t;
typedef __attribute__((ext_vector_type(8))) short bf16x8;
typedef __attribute__((ext_vector_type(4))) float f32x4;

#define LOG2E 1.4426950408889634f

// ---------------- helpers ----------------
__device__ __forceinline__ float sigf(float x) {
  x = fminf(fmaxf(x, -30.f), 30.f);
  return 1.f / (1.f + __expf(-x));
}
__device__ __forceinline__ ushort_t f2bf(float x) {
  unsigned int b = __float_as_uint(x);
  unsigned int lsb = (b >> 16) & 1u;
  b += 0x7fffu + lsb;
  return (ushort_t)(b >> 16);
}
__device__ __forceinline__ float bf2f(ushort_t u) {
  return __uint_as_float(((unsigned int)u) << 16);
}
// gate scale for exp2-form activations: rows of gate g (pos&3==2) carry
// 2*log2e, others log2e. Applied at every pre-activation producer.
__device__ __forceinline__ float gsc(int g3) {
  return (g3 == 2) ? (2.f * LOG2E) : LOG2E;
}

#define NPIX 3600
// gate-row permutation: LSTM row-space position rho holds real gate row
// G(rho) = (rho&3)*128 + (rho>>2)  => per cell c, gates i,f,g,o sit at
// positions 4c..4c+3.
__device__ __forceinline__ int gperm(int rho) {
  return ((rho & 3) << 7) + (rho >> 2);
}

// ------- gvec[b][n] = wih0[:,128:] @ gf[b] / 3600 (permuted, gate-scaled) ---
__global__ __launch_bounds__(256) void gvec_kernel(
    const float* __restrict__ wih0, const float* __restrict__ gf,
    float* __restrict__ gvec) {
  int i = blockIdx.x * 256 + threadIdx.x;  // 16384
  int b = i >> 9, n = i & 511;
  const float* wr = wih0 + gperm(n) * 192 + 128;
  const float* g = gf + b * 64;
  float a = 0.f;
#pragma unroll
  for (int k = 0; k < 64; ++k) a = fmaf(wr[k], g[k], a);
  gvec[i] = a * (1.f / 3600.f) * gsc(n & 3);
}

// ---- front: wprep (blocks 0-1988) + box stats (1989-6788) ------------------
__global__ __launch_bounds__(256) void front_kernel(
    const float* __restrict__ mv, const float* __restrict__ boxes,
    const int* __restrict__ ids, const float* __restrict__ agg_w1,
    const float* __restrict__ agg_b1, const float* __restrict__ agg_w2,
    const float* __restrict__ agg_b2, const float* __restrict__ bx_w1,
    const float* __restrict__ bx_b1, const float* __restrict__ bx_w2,
    const float* __restrict__ bx_b2, const float* __restrict__ id_table,
    ushort_t* __restrict__ obj_out, const float* __restrict__ conv2_w,
    const float* __restrict__ conv3_w, const float* __restrict__ wih0,
    const float* __restrict__ projW, const float* __restrict__ projb,
    const float* __restrict__ l0_b, const float* __restrict__ hbw1,
    const float* __restrict__ hcw1, const float* __restrict__ htw1,
    const float* __restrict__ htw2, const float* __restrict__ hbb1,
    const float* __restrict__ hcb1, const float* __restrict__ htb1,
    ushort_t* __restrict__ wc2, ushort_t* __restrict__ wc3,
    ushort_t* __restrict__ wAp, float* __restrict__ l0bp,
    ushort_t* __restrict__ whid, ushort_t* __restrict__ wt2,
    float* __restrict__ bhid) {
  if (blockIdx.x < 1989) {
    // ---- weight prep ----
    int i = blockIdx.x * 256 + threadIdx.x;
    if (i < 18432) {  // conv2 w -> [oc][kt][ic] bf16
      int oc = i / 288, r = i % 288, kt = r / 32, ic = r % 32;
      wc2[i] = f2bf(conv2_w[((oc * 32 + ic) * 3 + kt / 3) * 3 + kt % 3]);
      return;
    }
    i -= 18432;
    if (i < 36864) {  // conv3 w -> [oc][c][kt][ic] bf16
      int oc = i / 576, r = i % 576, c = r / 288, r2 = r % 288;
      int kt = r2 / 32, icl = r2 % 32, ic = c * 32 + icl;
      wc3[i] = f2bf(conv3_w[((oc * 64 + ic) * 3 + kt / 3) * 3 + kt % 3]);
      return;
    }
    i -= 36864;
    if (i < 98304) {  // W' = wih0[:, :128] @ projW, permuted + gate-scaled
      int n = i / 192, k = i % 192;
      int src = gperm(n);
      float a = 0.f;
      if (k < 160) {
        const float* wr = wih0 + src * 192;
        for (int j = 0; j < 128; ++j) a = fmaf(wr[j], projW[j * 160 + k], a);
      }
      wAp[i] = f2bf(a * gsc(n & 3));
      return;
    }
    i -= 98304;
    if (i < 512) {  // l0b' = l0_b + wih0[:, :128] @ proj_b, permuted + scaled
      int src = gperm(i);
      float a = l0_b[src];
      const float* wr = wih0 + src * 192;
      for (int j = 0; j < 128; ++j) a = fmaf(wr[j], projb[j], a);
      l0bp[i] = a * gsc(i & 3);
      return;
    }
    i -= 512;
    if (i < 98304) {  // concat head hidden weights
      int row = i >> 7, c = i & 127;
      float v = (row < 256)   ? hbw1[row * 128 + c]
                : (row < 512) ? hcw1[(row - 256) * 128 + c]
                              : htw1[(row - 512) * 128 + c];
      whid[i] = f2bf(v);
      return;
    }
    i -= 98304;
    if (i < 256000) {
      wt2[i] = f2bf(htw2[i]);
      return;
    }
    i -= 256000;
    if (i < 768)
      bhid[i] = (i < 256) ? hbb1[i] : (i < 512) ? hcb1[i - 256] : htb1[i - 512];
    return;
  }
  // ---- box stats + small MLPs: 2 boxes per block ----
  int bx = blockIdx.x - 1989;
  __shared__ float obj[2][160];
  __shared__ float hm[2][32];
  __shared__ float hbx[2][32];
  __shared__ float stats[2][8];
  __shared__ float boxf[2][4];
  __shared__ float red[2][2][8];
  int h = threadIdx.x >> 7;
  int t = threadIdx.x & 127;
  int blk = bx * 2 + h;  // box index 0..9599
  int b = blk / 300;
  float bx0 = boxes[blk * 4 + 0], by0 = boxes[blk * 4 + 1];
  float bx1 = boxes[blk * 4 + 2], by1 = boxes[blk * 4 + 3];
  const float HI = (float)(60.0 - 1e-6);
  float gx1 = fminf(fmaxf(bx0 * 60.f, 0.f), HI);
  float gy1 = fminf(fmaxf(by0 * 60.f, 0.f), HI);
  float gx2 = fminf(fmaxf(bx1 * 60.f, 0.f), HI);
  float gy2 = fminf(fmaxf(by1 * 60.f, 0.f), HI);
  float fx1 = floorf(gx1), fy1 = floorf(gy1);
  float fx2 = fmaxf(fx1 + 1.f, ceilf(gx2));
  float fy2 = fmaxf(fy1 + 1.f, ceilf(gy2));
  int ix1 = (int)fx1, iy1 = (int)fy1, ix2 = (int)fx2, iy2 = (int)fy2;
  int w = ix2 - ix1, hgt = iy2 - iy1;
  int area = w * hgt;
  float s0 = 0.f, s1 = 0.f, q0 = 0.f, q1 = 0.f;
  float mn0 = 1e9f, mn1 = 1e9f, mx0 = -1e9f, mx1 = -1e9f;
  const float* mv0 = mv + b * 2 * NPIX;
  const float* mv1 = mv0 + NPIX;
  for (int i = t; i < area; i += 128) {
    int r = i / w, cc = i - r * w;
    int yy = iy1 + r, xx = ix1 + cc;
    float v0 = mv0[yy * 60 + xx];
    float v1 = mv1[yy * 60 + xx];
    s0 += v0; q0 += v0 * v0; mn0 = fminf(mn0, v0); mx0 = fmaxf(mx0, v0);
    s1 += v1; q1 += v1 * v1; mn1 = fminf(mn1, v1); mx1 = fmaxf(mx1, v1);
  }
#pragma unroll
  for (int off = 32; off; off >>= 1) {
    s0 += __shfl_down(s0, off); s1 += __shfl_down(s1, off);
    q0 += __shfl_down(q0, off); q1 += __shfl_down(q1, off);
    mn0 = fminf(mn0, __shfl_down(mn0, off));
    mn1 = fminf(mn1, __shfl_down(mn1, off));
    mx0 = fmaxf(mx0, __shfl_down(mx0, off));
    mx1 = fmaxf(mx1, __shfl_down(mx1, off));
  }
  if ((t & 63) == 0) {
    int wv = t >> 6;
    red[h][wv][0] = s0; red[h][wv][1] = s1;
    red[h][wv][2] = q0; red[h][wv][3] = q1;
    red[h][wv][4] = mn0; red[h][wv][5] = mn1;
    red[h][wv][6] = mx0; red[h][wv][7] = mx1;
  }
  __syncthreads();
  if (t == 0) {
    float S0 = red[h][0][0] + red[h][1][0], S1 = red[h][0][1] + red[h][1][1];
    float Q0 = red[h][0][2] + red[h][1][2], Q1 = red[h][0][3] + red[h][1][3];
    float MN0 = fminf(red[h][0][4], red[h][1][4]);
    float MN1 = fminf(red[h][0][5], red[h][1][5]);
    float MX0 = fmaxf(red[h][0][6], red[h][1][6]);
    float MX1 = fmaxf(red[h][0][7], red[h][1][7]);
    float cnt = (float)area;
    float mean0 = S0 / cnt, mean1 = S1 / cnt;
    float var0 = (Q0 - cnt * mean0 * mean0) / fmaxf(cnt - 1.f, 1.f);
    float var1 = (Q1 - cnt * mean1 * mean1) / fmaxf(cnt - 1.f, 1.f);
    float sd0 = (cnt > 1.f) ? sqrtf(fmaxf(var0, 1e-12f)) : 0.f;
    float sd1 = (cnt > 1.f) ? sqrtf(fmaxf(var1, 1e-12f)) : 0.f;
    stats[h][0] = mean0; stats[h][1] = mean1; stats[h][2] = sd0;
    stats[h][3] = sd1; stats[h][4] = MN0; stats[h][5] = MX0;
    stats[h][6] = MN1; stats[h][7] = MX1;
    boxf[h][0] = bx0; boxf[h][1] = by0; boxf[h][2] = bx1; boxf[h][3] = by1;
  }
  __syncthreads();
  if (t < 32) {
    float a = agg_b1[t];
#pragma unroll
    for (int k = 0; k < 8; ++k) a = fmaf(stats[h][k], agg_w1[t * 8 + k], a);
    hm[h][t] = fmaxf(a, 0.f);
  } else if (t < 64) {
    int j = t - 32;
    float a = bx_b1[j];
#pragma unroll
    for (int k = 0; k < 4; ++k) a = fmaf(boxf[h][k], bx_w1[j * 4 + k], a);
    hbx[h][j] = fmaxf(a, 0.f);
  }
  __syncthreads();
  if (t < 64) {
    float a = bx_b2[t];
#pragma unroll
    for (int k = 0; k < 32; ++k) a = fmaf(hbx[h][k], bx_w2[t * 32 + k], a);
    obj[h][t] = a;
  } else {
    int j = t - 64;
    float a = agg_b2[j];
#pragma unroll
    for (int k = 0; k < 32; ++k) a = fmaf(hm[h][k], agg_w2[j * 32 + k], a);
    obj[h][96 + j] = a;
  }
  if (t < 32) {
    int id = ids[blk];
    id = min(max(id, 0), 999);
    obj[h][64 + t] = id_table[id * 32 + t];
  }
  __syncthreads();
  obj_out[(size_t)blk * 192 + t] = f2bf(obj[h][t]);
  if (t < 32) {
    obj_out[(size_t)blk * 192 + 128 + t] = f2bf(obj[h][128 + t]);
    obj_out[(size_t)blk * 192 + 160 + t] = 0;
  }
}

// ---------- fused conv1+conv2+conv3+avgpool: one block = 14x14 out tile -----
// Entire conv stack in LDS with halos (conv3 14x14 <- conv2 16x16 [-1 off]
// <- conv1 18x18 [-2 off] <- mv 20x20 [-3 off]); zero intermediate HBM
// traffic (x1u/x2u eliminated). Output = gf atomics only. Tiles: tq/tr 0..4,
// origin min(14*t, 46); overlap rows/cols excluded from pool (t==4 -> >=10).
// Out-of-image positions explicitly zeroed at every stage (SAME zero-pad).
__global__ __launch_bounds__(256) void convstack_kernel(
    const float* __restrict__ mv, const float* __restrict__ c1w,
    const float* __restrict__ c1b, const float* __restrict__ bg1,
    const float* __restrict__ bb1, const ushort_t* __restrict__ wc2,
    const float* __restrict__ c2b, const float* __restrict__ bg2,
    const float* __restrict__ bb2, const ushort_t* __restrict__ wc3,
    const float* __restrict__ c3b, const float* __restrict__ bg3,
    const float* __restrict__ bb3, float* __restrict__ gf) {
  __shared__ char smem[25920 + 37152];           // 63,072 B
  ushort_t* c1_lds = (ushort_t*)smem;            // [324][40] bf16
  ushort_t* c2_lds = (ushort_t*)(smem + 25920);  // [258][72] bf16 (+2 pad pos)
  float* mv_lds = (float*)(smem + 25920);        // [2][20][20] (aliases c2)
  int tid = threadIdx.x;
  int wv = tid >> 6, lane = tid & 63;
  int col = lane & 15, kg = lane >> 4;
  int b = blockIdx.y, tile = blockIdx.x;
  int tq = tile / 5, tr = tile % 5;
  int ty0 = (tq == 4) ? 46 : tq * 14;
  int tx0 = (tr == 4) ? 46 : tr * 14;
  // stage mv rows [ty0-3, ty0+16] x cols [tx0-3, tx0+16], zero-padded
  for (int i = tid; i < 800; i += 256) {
    int r = i % 400;
    int ch = i / 400, yy = r / 20, xx = r % 20;
    int gy = ty0 - 3 + yy, gx = tx0 - 3 + xx;
    float v = 0.f;
    if (gy >= 0 && gy < 60 && gx >= 0 && gx < 60)
      v = mv[((size_t)(b * 2 + ch) * 60 + gy) * 60 + gx];
    mv_lds[i] = v;
  }
  __syncthreads();
  // conv1 (2->32, BN+ReLU): 18x18 out, rows [ty0-2, ty0+15]
  {
    int oc = tid & 31;
    float s = bg1[oc] * rsqrtf(1.f + 1e-5f);
    float bias = fmaf(c1b[oc], s, bb1[oc]);
    float w1r[18];
#pragma unroll
    for (int k = 0; k < 18; ++k) w1r[k] = c1w[oc * 18 + k];
    for (int pos = tid >> 5; pos < 324; pos += 8) {
      int yy = pos / 18, xx = pos % 18;
      int gy = ty0 - 2 + yy, gx = tx0 - 2 + xx;
      ushort_t out = 0;
      if (gy >= 0 && gy < 60 && gx >= 0 && gx < 60) {
        float acc = 0.f;
#pragma unroll
        for (int ic = 0; ic < 2; ++ic)
#pragma unroll
          for (int ky = 0; ky < 3; ++ky)
#pragma unroll
            for (int kx = 0; kx < 3; ++kx)
              acc = fmaf(mv_lds[ic * 400 + (yy + ky) * 20 + xx + kx],
                         w1r[ic * 9 + ky * 3 + kx], acc);
        out = f2bf(fmaxf(fmaf(acc, s, bias), 0.f));
      }
      c1_lds[pos * 40 + oc] = out;
    }
  }
  __syncthreads();  // conv1 done; mv reads done (c2_lds aliasing now safe)
  int oc2 = wv * 16 + col;
  // conv2 (32->64, MFMA, BN+ReLU): 16x16 out, rows [ty0-1, ty0+14]
  {
    bf16x8 bw2[9];
#pragma unroll
    for (int kt = 0; kt < 9; ++kt)
      bw2[kt] = *(const bf16x8*)(wc2 + oc2 * 288 + kt * 32 + kg * 8);
    f32x4 a2[16];
#pragma unroll
    for (int m = 0; m < 16; ++m) a2[m] = (f32x4){0.f, 0.f, 0.f, 0.f};
#pragma unroll
    for (int kt = 0; kt < 9; ++kt) {
      int ky = kt / 3, kx = kt % 3;
#pragma unroll
      for (int m = 0; m < 16; ++m) {
        bf16x8 af = *(const bf16x8*)(
            &c1_lds[((m + ky) * 18 + col + kx) * 40 + kg * 8]);
        a2[m] =
            __builtin_amdgcn_mfma_f32_16x16x32_bf16(af, bw2[kt], a2[m], 0, 0, 0);
      }
    }
    float s = bg2[oc2] * rsqrtf(1.f + 1e-5f);
    float bias = fmaf(c2b[oc2], s, bb2[oc2]);
#pragma unroll
    for (int m = 0; m < 16; ++m) {
      int gy = ty0 - 1 + m;
#pragma unroll
      for (int r = 0; r < 4; ++r) {
        int gx = tx0 - 1 + kg * 4 + r;
        ushort_t o = 0;
        if (gy >= 0 && gy < 60 && gx >= 0 && gx < 60)
          o = f2bf(fmaxf(fmaf(a2[m][r], s, bias), 0.f));
        c2_lds[(m * 16 + kg * 4 + r) * 72 + oc2] = o;
      }
    }
  }
  __syncthreads();
  // conv3 (64->64, MFMA, BN+ReLU) + masked avgpool accumulate
  {
    bf16x8 bw3[2][9];
#pragma unroll
    for (int c = 0; c < 2; ++c)
#pragma unroll
      for (int kt = 0; kt < 9; ++kt)
        bw3[c][kt] =
            *(const bf16x8*)(wc3 + oc2 * 576 + c * 288 + kt * 32 + kg * 8);
    f32x4 a3[14];
#pragma unroll
    for (int m = 0; m < 14; ++m) a3[m] = (f32x4){0.f, 0.f, 0.f, 0.f};
#pragma unroll
    for (int c = 0; c < 2; ++c)
#pragma unroll
      for (int kt = 0; kt < 9; ++kt) {
        int ky = kt / 3, kx = kt % 3;
#pragma unroll
        for (int m = 0; m < 14; ++m) {
          bf16x8 af = *(const bf16x8*)(
              &c2_lds[((m + ky) * 16 + col + kx) * 72 + c * 32 + kg * 8]);
          a3[m] = __builtin_amdgcn_mfma_f32_16x16x32_bf16(af, bw3[c][kt],
                                                          a3[m], 0, 0, 0);
        }
      }
    float s = bg3[oc2] * rsqrtf(1.f + 1e-5f);
    float bias = fmaf(c3b[oc2], s, bb3[oc2]);
    float pool = 0.f;
#pragma unroll
    for (int m = 0; m < 14; ++m) {
      bool ym = (tq != 4) || (m >= 10);
#pragma unroll
      for (int r = 0; r < 4; ++r) {
        int px = kg * 4 + r;
        bool xm = (px < 14) && ((tr != 4) || (px >= 10));
        if (ym && xm) pool += fmaxf(fmaf(a3[m][r], s, bias), 0.f);
      }
    }
    pool += __shfl_xor(pool, 16);
    pool += __shfl_xor(pool, 32);
    if (lane < 16) atomicAdd(&gf[b * 64 + oc2], pool);
  }
}

// ---------------- bf16-W MFMA GEMM: C = act(A@W^T + b [+ gvec]) -------------
template <int ACT, bool OBF16, bool GVEC>
__global__ __launch_bounds__(256) void gemm_bf16w_kernel(
    const ushort_t* __restrict__ A, int lda, const ushort_t* __restrict__ W,
    const float* __restrict__ bias, void* __restrict__ C, int ldc, int M,
    int N, int K, const float* __restrict__ gvec) {
  __shared__ ushort_t As[128 * 64];
  __shared__ ushort_t Ws[64 * 64];
  int tid = threadIdx.x;
  int wv = tid >> 6, lane = tid & 63;
  int col = lane & 15, kg = lane >> 4;
  int wm = wv >> 1, wn = wv & 1;
  int m0 = blockIdx.x * 128, n0 = blockIdx.y * 64;
  f32x4 acc[4][2];
#pragma unroll
  for (int i = 0; i < 4; ++i)
#pragma unroll
    for (int j = 0; j < 2; ++j) acc[i][j] = (f32x4){0.f, 0.f, 0.f, 0.f};

  int nk = K >> 6;
  for (int kc = 0; kc < nk; ++kc) {
    if (kc) __syncthreads();
#pragma unroll
    for (int q = 0; q < 4; ++q) {
      int idx = q * 256 + tid;
      int row = idx >> 3, ch = idx & 7;
      uint4 v =
          *(const uint4*)(A + (size_t)(m0 + row) * lda + kc * 64 + ch * 8);
      *(uint4*)(&As[row * 64 + ((ch * 8) ^ ((row & 7) << 3))]) = v;
    }
#pragma unroll
    for (int q = 0; q < 2; ++q) {
      int idx = q * 256 + tid;
      int row = idx >> 3, ch = idx & 7;
      int n = n0 + row;
      uint4 v = make_uint4(0, 0, 0, 0);
      if (n < N) v = *(const uint4*)(W + (size_t)n * K + kc * 64 + ch * 8);
      *(uint4*)(&Ws[row * 64 + ((ch * 8) ^ ((row & 7) << 3))]) = v;
    }
    __syncthreads();
#pragma unroll
    for (int ks = 0; ks < 2; ++ks) {
      bf16x8 bfr[2], afr[4];
#pragma unroll
      for (int ni = 0; ni < 2; ++ni) {
        int row = wn * 32 + ni * 16 + col;
        bfr[ni] = *(const bf16x8*)(
            &Ws[row * 64 + ((ks * 32 + kg * 8) ^ ((row & 7) << 3))]);
      }
#pragma unroll
      for (int mi = 0; mi < 4; ++mi) {
        int row = wm * 64 + mi * 16 + col;
        afr[mi] = *(const bf16x8*)(
            &As[row * 64 + ((ks * 32 + kg * 8) ^ ((row & 7) << 3))]);
      }
#pragma unroll
      for (int mi = 0; mi < 4; ++mi)
#pragma unroll
        for (int ni = 0; ni < 2; ++ni)
          acc[mi][ni] = __builtin_amdgcn_mfma_f32_16x16x32_bf16(
              afr[mi], bfr[ni], acc[mi][ni], 0, 0, 0);
    }
  }
#pragma unroll
  for (int ni = 0; ni < 2; ++ni) {
    int n = n0 + wn * 32 + ni * 16 + col;
    float bn = (n < N) ? bias[n] : 0.f;
#pragma unroll
    for (int mi = 0; mi < 4; ++mi) {
      int mbase = m0 + wm * 64 + mi * 16 + kg * 4;
#pragma unroll
      for (int r = 0; r < 4; ++r) {
        float v = acc[mi][ni][r] + bn;
        if (GVEC) v += gvec[((mbase + r) / 300) * 512 + n];
        if (ACT == 1) v = fmaxf(v, 0.f);
        if (n < N) {
          if (OBF16)
            ((ushort_t*)C)[(size_t)(mbase + r) * ldc + n] = f2bf(v);
          else
            ((float*)C)[(size_t)(mbase + r) * ldc + n] = v;
        }
      }
    }
  }
}

// ---------------- small heads: hb2 (sigmoid, N=4) + hc2 (N=2) ---------------
__global__ __launch_bounds__(256) void head_small_kernel(
    const ushort_t* __restrict__ hid, const float* __restrict__ wb2,
    const float* __restrict__ bb2, const float* __restrict__ wc2,
    const float* __restrict__ bc2, float* __restrict__ outB,
    float* __restrict__ outC) {
  int idx = blockIdx.x * 256 + threadIdx.x;  // 9600*6
  int row = idx / 6, j = idx % 6;
  const ushort_t* h = hid + (size_t)row * 768 + (j < 4 ? 0 : 256);
  const float* wrow = (j < 4) ? wb2 + j * 256 : wc2 + (j - 4) * 256;
  float acc = (j < 4) ? bb2[j] : bc2[j - 4];
  for (int k = 0; k < 256; k += 8) {
    uint4 hv = *(const uint4*)(h + k);
    unsigned int ww[4] = {hv.x, hv.y, hv.z, hv.w};
#pragma unroll
    for (int q = 0; q < 4; ++q) {
      acc = fmaf(bf2f((ushort_t)(ww[q] & 0xffff)), wrow[k + 2 * q], acc);
      acc = fmaf(bf2f((ushort_t)(ww[q] >> 16)), wrow[k + 2 * q + 1], acc);
    }
  }
  float v = (j < 4) ? sigf(acc) : acc;
  if (j < 4) outB[row * 4 + j] = v;
  else outC[row * 2 + (j - 4)] = v;
}

// ---------------- fused pipelined 2-layer LSTM scan (= v9 core) --------------
#define LSTM_BAR() asm volatile("s_waitcnt lgkmcnt(0)\n\ts_barrier" ::: "memory")

__global__ __launch_bounds__(512) void lstm_fused_kernel(
    const float* __restrict__ pre0,  // [32][300][512] f32, permuted+scaled
    const float* __restrict__ whh0,  // [512,128]
    const float* __restrict__ wih1,  // [512,128]
    const float* __restrict__ whh1,  // [512,128]
    const float* __restrict__ b1,    // [512]
    float* __restrict__ pre1,        // [32][300][512] f32, permuted+scaled
    ushort_t* __restrict__ y0,       // [32][300][128] bf16 (L0 -> u)
    ushort_t* __restrict__ y1,       // [32][300][128] bf16
    float* __restrict__ outH, float* __restrict__ outC,
    unsigned int* __restrict__ flags)  // [8*32] padded
{
  __shared__ ushort_t h_lds[2][4][160];
  int tid = threadIdx.x;
  int w = tid >> 6, lane = tid & 63;
  int col = lane & 15, kg = lane >> 4;
  int bat = col & 3, q = col >> 2;
  int cell = (4 * w + q) * 4 + kg;
  float wsc = gsc(col & 3);  // A-row = col -> gate = col&3

  if (blockIdx.x < 8) {
    // ---------------- layer 0 ----------------
    int g = blockIdx.x;
    int b0 = g * 4;
    unsigned int* flagp = &flags[g * 32];
    for (int i = tid; i < 2 * 4 * 160; i += 512) ((ushort_t*)h_lds)[i] = 0;
    bf16x8 aW0[4][4];
#pragma unroll
    for (int j = 0; j < 4; ++j) {
      int rho = (4 * w + j) * 16 + col;
      int src = gperm(rho);
#pragma unroll
      for (int kt = 0; kt < 4; ++kt) {
        const float* s1 = whh0 + src * 128 + kt * 32 + kg * 8;
        bf16x8 f1;
#pragma unroll
        for (int qq = 0; qq < 8; ++qq) f1[qq] = (short)f2bf(s1[qq] * wsc);
        aW0[j][kt] = f1;
      }
    }
    const float* pg = pre0 + (size_t)(b0 + bat) * 300 * 512 + 4 * cell;
    ushort_t* yg0 = y0 + ((size_t)(b0 + bat) * 300) * 128 + cell;
    float c = 0.f, hout = 0.f;
    f32x4 p0v = *(const f32x4*)(pg);
    f32x4 p1v = *(const f32x4*)(pg + 512);
    __syncthreads();

    for (int s = 0; s < 300; ++s) {
      const ushort_t* hb = h_lds[s & 1][bat];
      bf16x8 bfr[4];
#pragma unroll
      for (int kt = 0; kt < 4; ++kt)
        bfr[kt] = *(const bf16x8*)(hb + kt * 32 + kg * 8);
      f32x4 a0 = {0.f, 0.f, 0.f, 0.f}, a1 = a0, a2 = a0, a3 = a0;
#pragma unroll
      for (int kt = 0; kt < 4; ++kt) {
        a0 = __builtin_amdgcn_mfma_f32_16x16x32_bf16(aW0[0][kt], bfr[kt], a0, 0, 0, 0);
        a1 = __builtin_amdgcn_mfma_f32_16x16x32_bf16(aW0[1][kt], bfr[kt], a1, 0, 0, 0);
        a2 = __builtin_amdgcn_mfma_f32_16x16x32_bf16(aW0[2][kt], bfr[kt], a2, 0, 0, 0);
        a3 = __builtin_amdgcn_mfma_f32_16x16x32_bf16(aW0[3][kt], bfr[kt], a3, 0, 0, 0);
      }
      // static select of own tile (q uniform per lane; cndmask, no scratch)
      f32x4 z = a0;
      if (q == 1) z = a1;
      if (q == 2) z = a2;
      if (q == 3) z = a3;
      {
        float zi = z[0] + p0v[0];
        float zf = z[1] + p0v[1];
        float zg = z[2] + p0v[2];
        float zo = z[3] + p0v[3];
        float vi = __builtin_amdgcn_rcpf(1.f + __builtin_amdgcn_exp2f(-zi));
        float vf = __builtin_amdgcn_rcpf(1.f + __builtin_amdgcn_exp2f(-zf));
        float vg = 1.f - 2.f * __builtin_amdgcn_rcpf(
                              __builtin_amdgcn_exp2f(zg) + 1.f);
        float vo = __builtin_amdgcn_rcpf(1.f + __builtin_amdgcn_exp2f(-zo));
        c = vf * c + vi * vg;
        hout = vo * (1.f - 2.f * __builtin_amdgcn_rcpf(
                             __builtin_amdgcn_exp2f(2.f * LOG2E * c) + 1.f));
        ushort_t hv = f2bf(hout);
        h_lds[(s + 1) & 1][bat][cell] = hv;
        __builtin_nontemporal_store(hv, yg0 + (size_t)s * 128);
        p0v = p1v;
        int sn = (s + 2 < 300) ? s + 2 : 299;
        p1v = *(const f32x4*)(pg + (size_t)sn * 512);
      }
      // 2 vmem ops/step; vmcnt(6) = 3 steps in flight => y0(<=s-3) retired
      asm volatile("s_waitcnt vmcnt(6)" ::: "memory");
      LSTM_BAR();
      if (tid == 0 && s >= 3)
        __hip_atomic_store(flagp, (unsigned int)(s - 3), __ATOMIC_RELAXED,
                           __HIP_MEMORY_SCOPE_AGENT);
    }
    asm volatile("s_waitcnt vmcnt(0)" ::: "memory");
    __syncthreads();
    if (tid == 0)
      __hip_atomic_store(flagp, 300u, __ATOMIC_RELAXED,
                         __HIP_MEMORY_SCOPE_AGENT);
    outH[(b0 + bat) * 128 + cell] = hout;
    outC[(b0 + bat) * 128 + cell] = c;
  } else if (blockIdx.x < 16) {
    // ---------------- layer 1 (mirror of L0, p from pre1 via u-flag) --------
    int g = blockIdx.x - 8;
    int b0 = g * 4;
    unsigned int* flagp = &flags[g * 32 + 16];
    for (int i = tid; i < 2 * 4 * 160; i += 512) ((ushort_t*)h_lds)[i] = 0;
    bf16x8 aW[4][4];
#pragma unroll
    for (int j = 0; j < 4; ++j) {
      int rho = (4 * w + j) * 16 + col;
      int src = gperm(rho);
#pragma unroll
      for (int kt = 0; kt < 4; ++kt) {
        const float* s1 = whh1 + src * 128 + kt * 32 + kg * 8;
        bf16x8 f1;
#pragma unroll
        for (int qq = 0; qq < 8; ++qq) f1[qq] = (short)f2bf(s1[qq] * wsc);
        aW[j][kt] = f1;
      }
    }
    float bi = b1[cell] * LOG2E, bff = b1[128 + cell] * LOG2E;
    float bgg = b1[256 + cell] * (2.f * LOG2E), boo = b1[384 + cell] * LOG2E;
    const float* pg = pre1 + (size_t)(b0 + bat) * 300 * 512 + 4 * cell;
    ushort_t* yg = y1 + (size_t)(b0 + bat) * 300 * 128 + cell;
    float c = 0.f, hout = 0.f;
    unsigned int fc = 0;
    f32x4 p0v, p1v;
    do {
      fc = __hip_atomic_load(flagp, __ATOMIC_RELAXED,
                             __HIP_MEMORY_SCOPE_AGENT);
      if (fc < 1) __builtin_amdgcn_s_sleep(2);
    } while (fc < 1);
    asm volatile("" ::: "memory");
    p0v = __builtin_nontemporal_load((const f32x4*)(pg));
    while (fc < 2) {
      fc = __hip_atomic_load(flagp, __ATOMIC_RELAXED,
                             __HIP_MEMORY_SCOPE_AGENT);
      if (fc < 2) __builtin_amdgcn_s_sleep(2);
    }
    asm volatile("" ::: "memory");
    p1v = __builtin_nontemporal_load((const f32x4*)(pg + 512));
    __syncthreads();

    for (int t = 0; t < 300; ++t) {
      // eager flag read: issue now, consume at the prefetch point below
      unsigned int fcn = __hip_atomic_load(flagp, __ATOMIC_RELAXED,
                                           __HIP_MEMORY_SCOPE_AGENT);
      const ushort_t* hb = h_lds[t & 1][bat];
      bf16x8 bfr[4];
#pragma unroll
      for (int kt = 0; kt < 4; ++kt)
        bfr[kt] = *(const bf16x8*)(hb + kt * 32 + kg * 8);
      f32x4 a0 = {0.f, 0.f, 0.f, 0.f}, a1 = a0, a2 = a0, a3 = a0;
#pragma unroll
      for (int kt = 0; kt < 4; ++kt) {
        a0 = __builtin_amdgcn_mfma_f32_16x16x32_bf16(aW[0][kt], bfr[kt], a0, 0, 0, 0);
        a1 = __builtin_amdgcn_mfma_f32_16x16x32_bf16(aW[1][kt], bfr[kt], a1, 0, 0, 0);
        a2 = __builtin_amdgcn_mfma_f32_16x16x32_bf16(aW[2][kt], bfr[kt], a2, 0, 0, 0);
        a3 = __builtin_amdgcn_mfma_f32_16x16x32_bf16(aW[3][kt], bfr[kt], a3, 0, 0, 0);
      }
      f32x4 z = a0;
      if (q == 1) z = a1;
      if (q == 2) z = a2;
      if (q == 3) z = a3;
      {
        float zi = z[0] + p0v[0] + bi;
        float zf = z[1] + p0v[1] + bff;
        float zg = z[2] + p0v[2] + bgg;
        float zo = z[3] + p0v[3] + boo;
        float vi = __builtin_amdgcn_rcpf(1.f + __builtin_amdgcn_exp2f(-zi));
        float vf = __builtin_amdgcn_rcpf(1.f + __builtin_amdgcn_exp2f(-zf));
        float vg = 1.f - 2.f * __builtin_amdgcn_rcpf(
                              __builtin_amdgcn_exp2f(zg) + 1.f);
        float vo = __builtin_amdgcn_rcpf(1.f + __builtin_amdgcn_exp2f(-zo));
        c = vf * c + vi * vg;
        hout = vo * (1.f - 2.f * __builtin_amdgcn_rcpf(
                             __builtin_amdgcn_exp2f(2.f * LOG2E * c) + 1.f));
        ushort_t hv = f2bf(hout);
        h_lds[(t + 1) & 1][bat][cell] = hv;
        yg[(size_t)t * 128] = hv;
        p0v = p1v;
        if (t + 2 < 300) {
          unsigned int need = (unsigned int)(t + 3);
          if (fcn > fc) fc = fcn;
          if (fc < need) {
            do {
              fc = __hip_atomic_load(flagp, __ATOMIC_RELAXED,
                                     __HIP_MEMORY_SCOPE_AGENT);
              if (fc < need) __builtin_amdgcn_s_sleep(2);
            } while (fc < need);
            asm volatile("" ::: "memory");
          }
          p1v = __builtin_nontemporal_load(
              (const f32x4*)(pg + (size_t)(t + 2) * 512));
        }
      }
      LSTM_BAR();
    }
    outH[4096 + (b0 + bat) * 128 + cell] = hout;
    outC[4096 + (b0 + bat) * 128 + cell] = c;
  } else {
    // ---------------- u-blocks: pre1[t] = Wih1 @ y0[t], 12-step chunks ------
    int g = blockIdx.x - 16;
    int b0 = g * 4;
    unsigned int* flag0 = &flags[g * 32];
    unsigned int* flag1 = &flags[g * 32 + 16];
    bf16x8 aU[4][4];
#pragma unroll
    for (int j = 0; j < 4; ++j) {
      int rho = (4 * w + j) * 16 + col;
      int src = gperm(rho);
#pragma unroll
      for (int kt = 0; kt < 4; ++kt) {
        const float* s2 = wih1 + src * 128 + kt * 32 + kg * 8;
        bf16x8 f2;
#pragma unroll
        for (int qq = 0; qq < 8; ++qq) f2[qq] = (short)f2bf(s2[qq] * wsc);
        aU[j][kt] = f2;
      }
    }
    int bb = col & 3;   // batch within group (B-col -> (batch, step))
    int ts = col >> 2;  // step within 4-step col-tile
    const ushort_t* yb = y0 + ((size_t)(b0 + bb) * 300) * 128 + kg * 8;
    unsigned int fc = 0;
    for (int t0 = 0; t0 < 300; t0 += 12) {
      unsigned int need = (unsigned int)(t0 + 11);
      while (fc < need) {
        fc = __hip_atomic_load(flag0, __ATOMIC_RELAXED,
                               __HIP_MEMORY_SCOPE_AGENT);
        if (fc < need) __builtin_amdgcn_s_sleep(2);
      }
      asm volatile("" ::: "memory");
      f32x4 acc[4][3];
#pragma unroll
      for (int j = 0; j < 4; ++j)
#pragma unroll
        for (int ct = 0; ct < 3; ++ct) acc[j][ct] = (f32x4){0.f, 0.f, 0.f, 0.f};
#pragma unroll
      for (int ct = 0; ct < 3; ++ct) {
        int t = t0 + ct * 4 + ts;
        bf16x8 bfr[4];
#pragma unroll
        for (int kt = 0; kt < 4; ++kt)
          bfr[kt] = __builtin_nontemporal_load(
              (const bf16x8*)(yb + (size_t)t * 128 + kt * 32));
#pragma unroll
        for (int kt = 0; kt < 4; ++kt) {
          acc[0][ct] = __builtin_amdgcn_mfma_f32_16x16x32_bf16(aU[0][kt], bfr[kt], acc[0][ct], 0, 0, 0);
          acc[1][ct] = __builtin_amdgcn_mfma_f32_16x16x32_bf16(aU[1][kt], bfr[kt], acc[1][ct], 0, 0, 0);
          acc[2][ct] = __builtin_amdgcn_mfma_f32_16x16x32_bf16(aU[2][kt], bfr[kt], acc[2][ct], 0, 0, 0);
          acc[3][ct] = __builtin_amdgcn_mfma_f32_16x16x32_bf16(aU[3][kt], bfr[kt], acc[3][ct], 0, 0, 0);
        }
      }
#pragma unroll
      for (int ct = 0; ct < 3; ++ct) {
        int t = t0 + ct * 4 + ts;
        float* pd = pre1 + ((size_t)(b0 + bb) * 300 + t) * 512 + kg * 4;
#pragma unroll
        for (int j = 0; j < 4; ++j)
          __builtin_nontemporal_store(acc[j][ct],
                                      (f32x4*)(pd + (4 * w + j) * 16));
      }
      asm volatile("s_waitcnt vmcnt(0)" ::: "memory");
      __syncthreads();
      if (tid == 0)
        __hip_atomic_store(flag1, (unsigned int)(t0 + 12), __ATOMIC_RELAXED,
                           __HIP_MEMORY_SCOPE_AGENT);
    }
  }
}

// ---------------- launch ----------------
extern "C" void kernel_launch(void* const* d_in, const int* in_sizes, int n_in,
                              void* d_out, int out_size, void* d_ws,
                              size_t ws_size, hipStream_t stream) {
  const float* mv = (const float*)d_in[0];
  const float* boxes = (const float*)d_in[1];
  const int* track_ids = (const int*)d_in[2];
  const float* conv1_w = (const float*)d_in[3];
  const float* conv1_b = (const float*)d_in[4];
  const float* bn1_g = (const float*)d_in[5];
  const float* bn1_b = (const float*)d_in[6];
  const float* conv2_w = (const float*)d_in[7];
  const float* conv2_b = (const float*)d_in[8];
  const float* bn2_g = (const float*)d_in[9];
  const float* bn2_b = (const float*)d_in[10];
  const float* conv3_w = (const float*)d_in[11];
  const float* conv3_b = (const float*)d_in[12];
  const float* bn3_g = (const float*)d_in[13];
  const float* bn3_b = (const float*)d_in[14];
  const float* agg_w1 = (const float*)d_in[15];
  const float* agg_b1 = (const float*)d_in[16];
  const float* agg_w2 = (const float*)d_in[17];
  const float* agg_b2 = (const float*)d_in[18];
  const float* bx_w1 = (const float*)d_in[19];
  const float* bx_b1 = (const float*)d_in[20];
  const float* bx_w2 = (const float*)d_in[21];
  const float* bx_b2 = (const float*)d_in[22];
  const float* id_table = (const float*)d_in[23];
  const float* proj_w = (const float*)d_in[24];
  const float* proj_b = (const float*)d_in[25];
  const float* l0_wih = (const float*)d_in[27];
  const float* l0_whh = (const float*)d_in[28];
  const float* l0_b = (const float*)d_in[29];
  const float* l1_wih = (const float*)d_in[30];
  const float* l1_whh = (const float*)d_in[31];
  const float* l1_b = (const float*)d_in[32];
  const float* hb_w1 = (const float*)d_in[33];
  const float* hb_b1 = (const float*)d_in[34];
  const float* hb_w2 = (const float*)d_in[35];
  const float* hb_b2 = (const float*)d_in[36];
  const float* hc_w1 = (const float*)d_in[37];
  const float* hc_b1 = (const float*)d_in[38];
  const float* hc_w2 = (const float*)d_in[39];
  const float* hc_b2 = (const float*)d_in[40];
  const float* ht_w1 = (const float*)d_in[41];
  const float* ht_b1 = (const float*)d_in[42];
  const float* ht_w2 = (const float*)d_in[43];
  const float* ht_b2 = (const float*)d_in[44];

  char* wsb = (char*)d_ws;
  float* pre0 = (float*)(wsb + 0);               // 19,660,800 B
  ushort_t* hid = (ushort_t*)(wsb + 0);          // 14,745,600 B (alias, tail)
  ushort_t* y0g = (ushort_t*)(wsb + 19660800);   // 2,457,600 B
  float* gf = (float*)(wsb + 22118400);          // 8,192 B
  ushort_t* obj = (ushort_t*)(wsb + 22126592);   // 3,686,400 B
  float* pre1 = (float*)(wsb + 25812992);        // 19,660,800 B
  ushort_t* y1b = (ushort_t*)(wsb + 45473792);   // 2,457,600 B
  unsigned int* flags = (unsigned int*)(wsb + 47931392);  // 1,024 B
  ushort_t* wAp = (ushort_t*)(wsb + 47932416);   // 196,608 B
  ushort_t* whid = (ushort_t*)(wsb + 48129024);  // 196,608 B
  ushort_t* wt2 = (ushort_t*)(wsb + 48325632);   // 512,000 B
  float* bhid = (float*)(wsb + 48837632);        // 3,072 B
  float* l0bp = (float*)(wsb + 48840704);        // 2,048 B
  float* gvec = (float*)(wsb + 48842752);        // 65,536 B
  ushort_t* wc2 = (ushort_t*)(wsb + 48908288);   // 36,864 B
  ushort_t* wc3 = (ushort_t*)(wsb + 48945152);   // 73,728 B

  float* outB = (float*)d_out;    // [32,300,4]
  float* outC = outB + 38400;     // [32,300,2]
  float* outT = outB + 57600;     // [32,300,1000]
  float* outH = outB + 9657600;   // [2,32,128]
  float* outCc = outB + 9665792;  // [2,32,128]

  hipMemsetAsync(gf, 0, 2048 * sizeof(float), stream);
  hipMemsetAsync(flags, 0, 1024, stream);

  front_kernel<<<6789, 256, 0, stream>>>(
      mv, boxes, track_ids, agg_w1, agg_b1, agg_w2, agg_b2, bx_w1, bx_b1,
      bx_w2, bx_b2, id_table, obj, conv2_w, conv3_w, l0_wih, proj_w, proj_b,
      l0_b, hb_w1, hc_w1, ht_w1, ht_w2, hb_b1, hc_b1, ht_b1, wc2, wc3, wAp,
      l0bp, whid, wt2, bhid);
  convstack_kernel<<<dim3(25, 32), 256, 0, stream>>>(
      mv, conv1_w, conv1_b, bn1_g, bn1_b, wc2, conv2_b, bn2_g, bn2_b, wc3,
      conv3_b, bn3_g, bn3_b, gf);
  gvec_kernel<<<64, 256, 0, stream>>>(l0_wih, gf, gvec);
  gemm_bf16w_kernel<0, false, true><<<dim3(75, 8), 256, 0, stream>>>(
      obj, 192, wAp, l0bp, pre0, 512, 9600, 512, 192, gvec);
  lstm_fused_kernel<<<24, 512, 0, stream>>>(pre0, l0_whh, l1_wih, l1_whh,
                                            l1_b, pre1, y0g, y1b, outH, outCc,
                                            flags);
  gemm_bf16w_kernel<1, true, false><<<dim3(75, 12), 256, 0, stream>>>(
      y1b, 128, whid, bhid, hid, 768, 9600, 768, 128, nullptr);
  head_small_kernel<<<225, 256, 0, stream>>>(hid, hb_w2, hb_b2, hc_w2, hc_b2,
                                             outB, outC);
  gemm_bf16w_kernel<0, false, false><<<dim3(75, 16), 256, 0, stream>>>(
      hid + 512, 768, wt2, ht_b2, outT, 1000, 9600, 1000, 256, nullptr);
}